// Round 2
// baseline (7351.958 us; speedup 1.0000x reference)
//
#include <hip/hip_runtime.h>
#include <hip/hip_bf16.h>
#include <math.h>

// Problem constants
#define B_SZ   8
#define SEQ    2048
#define DMODEL 512
#define DEPTH  2
#define DSTATE 16
#define DCONV  4
#define DINNER 1024
#define DTRANK 32
#define ROWS   (B_SZ * SEQ)          // 16384
#define DBCW   (DTRANK + 2 * DSTATE) // 64

__device__ __forceinline__ float silu_f(float v) {
    return v / (1.f + expf(-v));
}

// ---------------------------------------------------------------- LayerNorm
__global__ __launch_bounds__(256) void ln_kernel(const float* __restrict__ x,
                                                 const float* __restrict__ w,
                                                 const float* __restrict__ b,
                                                 float* __restrict__ out) {
    int r = blockIdx.x;
    int tid = threadIdx.x;
    const float* xr = x + (size_t)r * DMODEL;
    float2 v = *(const float2*)(xr + tid * 2);
    float s = v.x + v.y;
    float s2 = v.x * v.x + v.y * v.y;
    #pragma unroll
    for (int off = 1; off < 64; off <<= 1) {
        s  += __shfl_xor(s, off);
        s2 += __shfl_xor(s2, off);
    }
    __shared__ float ws[4], ws2[4];
    int wid = tid >> 6, lane = tid & 63;
    if (lane == 0) { ws[wid] = s; ws2[wid] = s2; }
    __syncthreads();
    float ts = ws[0] + ws[1] + ws[2] + ws[3];
    float ts2 = ws2[0] + ws2[1] + ws2[2] + ws2[3];
    float mean = ts * (1.f / DMODEL);
    float var = ts2 * (1.f / DMODEL) - mean * mean;
    float inv = rsqrtf(var + 1e-5f);
    float2 o;
    o.x = (v.x - mean) * inv * w[tid * 2] + b[tid * 2];
    o.y = (v.y - mean) * inv * w[tid * 2 + 1] + b[tid * 2 + 1];
    *(float2*)(out + (size_t)r * DMODEL + tid * 2) = o;
}

// ---------------------------------------------------------------- GEMM  C = A(MxK) * W(NxK)^T  (+ res)
// BM=BN=64, BK=16, 256 threads, 4x4 microtile per thread.
template <bool RES>
__global__ __launch_bounds__(256) void gemm_tn(const float* __restrict__ A,
                                               const float* __restrict__ W,
                                               const float* __restrict__ res,
                                               float* __restrict__ C,
                                               int M, int N, int K) {
    __shared__ float As[16][64];
    __shared__ float Bs[16][64];
    int tid = threadIdx.x;
    int n0 = blockIdx.x * 64;
    int m0 = blockIdx.y * 64;
    int tx = tid & 15, ty = tid >> 4;
    int lr = tid >> 2;          // 0..63 tile row
    int lk = (tid & 3) * 4;     // 0,4,8,12
    const float* Aptr = A + (size_t)(m0 + lr) * K + lk;
    const float* Wptr = W + (size_t)(n0 + lr) * K + lk;
    float acc[4][4] = {};
    for (int k0 = 0; k0 < K; k0 += 16) {
        float4 av = *(const float4*)(Aptr + k0);
        float4 bv = *(const float4*)(Wptr + k0);
        __syncthreads();
        As[lk + 0][lr] = av.x; As[lk + 1][lr] = av.y;
        As[lk + 2][lr] = av.z; As[lk + 3][lr] = av.w;
        Bs[lk + 0][lr] = bv.x; Bs[lk + 1][lr] = bv.y;
        Bs[lk + 2][lr] = bv.z; Bs[lk + 3][lr] = bv.w;
        __syncthreads();
        #pragma unroll
        for (int kk = 0; kk < 16; ++kk) {
            float4 a = *(const float4*)&As[kk][ty * 4];
            float4 b = *(const float4*)&Bs[kk][tx * 4];
            float ar[4] = {a.x, a.y, a.z, a.w};
            float br[4] = {b.x, b.y, b.z, b.w};
            #pragma unroll
            for (int i = 0; i < 4; ++i)
                #pragma unroll
                for (int j = 0; j < 4; ++j)
                    acc[i][j] += ar[i] * br[j];
        }
    }
    #pragma unroll
    for (int i = 0; i < 4; ++i) {
        int m = m0 + ty * 4 + i;
        size_t off = (size_t)m * N + n0 + tx * 4;
        float4 v = {acc[i][0], acc[i][1], acc[i][2], acc[i][3]};
        if (RES) {
            float4 r4 = *(const float4*)(res + off);
            v.x += r4.x; v.y += r4.y; v.z += r4.z; v.w += r4.w;
        }
        *(float4*)(C + off) = v;
    }
}

// ---------------------------------------------------------------- x_proj GEMM with fused depthwise conv + SiLU on A
// dbc[r, f] = sum_e silu(conv(xi, r, e) + cb[e]) * xpw[f, e]
// M=16384 rows, N=64 (one block column), K=1024.
__global__ __launch_bounds__(256) void gemm_xproj(const float* __restrict__ xz,
                                                  const float* __restrict__ xpw,
                                                  const float* __restrict__ cw,
                                                  const float* __restrict__ cb,
                                                  float* __restrict__ dbc) {
    __shared__ float As[16][64];
    __shared__ float Bs[16][64];
    int tid = threadIdx.x;
    int m0 = blockIdx.x * 64;
    int tx = tid & 15, ty = tid >> 4;
    int lr = tid >> 2;          // 0..63
    int lk = (tid & 3) * 4;     // 0,4,8,12
    int r = m0 + lr;
    int l = r & (SEQ - 1);
    const float* xp = xz + (size_t)r * (2 * DINNER) + lk;
    const float* wp = xpw + (size_t)lr * DINNER + lk;   // lr = f row (N=64)
    float acc[4][4] = {};
    const float4 zero4 = {0.f, 0.f, 0.f, 0.f};
    for (int e0 = 0; e0 < DINNER; e0 += 16) {
        float4 x0  = *(const float4*)(xp + e0);
        float4 xm1 = (l >= 1) ? *(const float4*)(xp + e0 - 1 * 2 * DINNER) : zero4;
        float4 xm2 = (l >= 2) ? *(const float4*)(xp + e0 - 2 * 2 * DINNER) : zero4;
        float4 xm3 = (l >= 3) ? *(const float4*)(xp + e0 - 3 * 2 * DINNER) : zero4;
        float4 cb4 = *(const float4*)(cb + e0 + lk);
        float4 cwa = *(const float4*)(cw + (e0 + lk + 0) * 4);
        float4 cwb = *(const float4*)(cw + (e0 + lk + 1) * 4);
        float4 cwc = *(const float4*)(cw + (e0 + lk + 2) * 4);
        float4 cwd = *(const float4*)(cw + (e0 + lk + 3) * 4);
        float u0 = silu_f(cb4.x + cwa.x * xm3.x + cwa.y * xm2.x + cwa.z * xm1.x + cwa.w * x0.x);
        float u1 = silu_f(cb4.y + cwb.x * xm3.y + cwb.y * xm2.y + cwb.z * xm1.y + cwb.w * x0.y);
        float u2 = silu_f(cb4.z + cwc.x * xm3.z + cwc.y * xm2.z + cwc.z * xm1.z + cwc.w * x0.z);
        float u3 = silu_f(cb4.w + cwd.x * xm3.w + cwd.y * xm2.w + cwd.z * xm1.w + cwd.w * x0.w);
        float4 bv = *(const float4*)(wp + e0);
        __syncthreads();
        As[lk + 0][lr] = u0; As[lk + 1][lr] = u1;
        As[lk + 2][lr] = u2; As[lk + 3][lr] = u3;
        Bs[lk + 0][lr] = bv.x; Bs[lk + 1][lr] = bv.y;
        Bs[lk + 2][lr] = bv.z; Bs[lk + 3][lr] = bv.w;
        __syncthreads();
        #pragma unroll
        for (int kk = 0; kk < 16; ++kk) {
            float4 a = *(const float4*)&As[kk][ty * 4];
            float4 b = *(const float4*)&Bs[kk][tx * 4];
            float ar[4] = {a.x, a.y, a.z, a.w};
            float br[4] = {b.x, b.y, b.z, b.w};
            #pragma unroll
            for (int i = 0; i < 4; ++i)
                #pragma unroll
                for (int j = 0; j < 4; ++j)
                    acc[i][j] += ar[i] * br[j];
        }
    }
    #pragma unroll
    for (int i = 0; i < 4; ++i) {
        int m = m0 + ty * 4 + i;
        size_t off = (size_t)m * DBCW + tx * 4;
        float4 v = {acc[i][0], acc[i][1], acc[i][2], acc[i][3]};
        *(float4*)(dbc + off) = v;
    }
}

// ---------------------------------------------------------------- fused selective scan
// conv+SiLU (rolling window) + dt_proj + softplus + scan + gate, all in one.
// block: 256 threads = 16 (b,e) pairs x 16 states. 512 blocks.
#define SCHUNK 8
__global__ __launch_bounds__(256) void scan_fused(const float* __restrict__ xz,
                                                  const float* __restrict__ dbc,
                                                  const float* __restrict__ cw,
                                                  const float* __restrict__ cb,
                                                  const float* __restrict__ dtw,
                                                  const float* __restrict__ dtb,
                                                  const float* __restrict__ Alog,
                                                  const float* __restrict__ Dp,
                                                  float* __restrict__ y) {
    int tid = threadIdx.x;
    int pair = tid >> 4, n = tid & 15;
    int blk = blockIdx.x;
    int b = blk >> 6;                        // 64 e-groups per batch
    int e = ((blk & 63) << 4) + pair;
    float a = -expf(Alog[e * DSTATE + n]);
    float w0 = cw[e * 4 + 0], w1 = cw[e * 4 + 1], w2 = cw[e * 4 + 2], w3 = cw[e * 4 + 3];
    float cbe = cb[e], dtbe = dtb[e], dpe = Dp[e];
    float dw0 = dtw[e * DTRANK + 2 * n], dw1 = dtw[e * DTRANK + 2 * n + 1];
    const float* xzrow = xz + (size_t)b * SEQ * (2 * DINNER) + e;
    const float* dbrow = dbc + (size_t)b * SEQ * DBCW;
    float* yrow = y + (size_t)b * SEQ * DINNER + e;

    float h = 0.f, x1 = 0.f, x2 = 0.f, x3 = 0.f;
    float qx[2][SCHUNK], qz[2][SCHUNK], qd0[2][SCHUNK], qd1[2][SCHUNK], qB[2][SCHUNK], qC[2][SCHUNK];

    auto load_chunk = [&](int c, int buf) {
        const float* xp = xzrow + (size_t)c * SCHUNK * (2 * DINNER);
        const float* dp = dbrow + (size_t)c * SCHUNK * DBCW;
        #pragma unroll
        for (int j = 0; j < SCHUNK; ++j) {
            qx[buf][j]  = xp[(size_t)j * (2 * DINNER)];
            qz[buf][j]  = xp[(size_t)j * (2 * DINNER) + DINNER];
            qd0[buf][j] = dp[j * DBCW + 2 * n];
            qd1[buf][j] = dp[j * DBCW + 2 * n + 1];
            qB[buf][j]  = dp[j * DBCW + DTRANK + n];
            qC[buf][j]  = dp[j * DBCW + DTRANK + DSTATE + n];
        }
    };
    load_chunk(0, 0);
    const int nc = SEQ / SCHUNK;
    for (int c = 0; c < nc; ++c) {
        int cur = c & 1;
        if (c + 1 < nc) load_chunk(c + 1, cur ^ 1);
        #pragma unroll
        for (int j = 0; j < SCHUNK; ++j) {
            float xi = qx[cur][j];
            float u = cbe + w0 * x3 + w1 * x2 + w2 * x1 + w3 * xi;
            x3 = x2; x2 = x1; x1 = xi;
            u = silu_f(u);
            float p = qd0[cur][j] * dw0 + qd1[cur][j] * dw1;
            p += __shfl_xor(p, 1);
            p += __shfl_xor(p, 2);
            p += __shfl_xor(p, 4);
            p += __shfl_xor(p, 8);
            float s = p + dtbe;
            float delta = (s > 20.f) ? s : log1pf(expf(s));
            float dA = expf(delta * a);
            h = dA * h + (delta * u) * qB[cur][j];
            float yp = h * qC[cur][j];
            yp += __shfl_xor(yp, 1);
            yp += __shfl_xor(yp, 2);
            yp += __shfl_xor(yp, 4);
            yp += __shfl_xor(yp, 8);
            if (n == 0) {
                float zz = qz[cur][j];
                int t = c * SCHUNK + j;
                yrow[(size_t)t * DINNER] = (yp + u * dpe) * silu_f(zz);
            }
        }
    }
}

// ---------------------------------------------------------------- launch
extern "C" void kernel_launch(void* const* d_in, const int* in_sizes, int n_in,
                              void* d_out, int out_size, void* d_ws, size_t ws_size,
                              hipStream_t stream) {
    const float* x_in   = (const float*)d_in[0];
    const float* ln_w   = (const float*)d_in[1];
    const float* ln_b   = (const float*)d_in[2];
    const float* inw    = (const float*)d_in[3];
    const float* convw  = (const float*)d_in[4];
    const float* convb  = (const float*)d_in[5];
    const float* xpw    = (const float*)d_in[6];
    const float* dtw    = (const float*)d_in[7];
    const float* dtb    = (const float*)d_in[8];
    const float* Alog   = (const float*)d_in[9];
    const float* Dp     = (const float*)d_in[10];
    const float* outw   = (const float*)d_in[11];
    float* out = (float*)d_out;

    // workspace carve-up (floats) — total 51,380,224 floats = 205.5 MB
    float* ws   = (float*)d_ws;
    float* xz   = ws;                                    // ROWS*2*DINNER = 33,554,432
    float* ybuf = xz + (size_t)ROWS * 2 * DINNER;        // ROWS*DINNER   = 16,777,216
    float* xn   = ybuf;                                  // alias: xn dead before scan writes ybuf
    float* dbc  = ybuf + (size_t)ROWS * DINNER;          // ROWS*DBCW     =  1,048,576

    const dim3 blk256(256);

    for (int i = 0; i < DEPTH; ++i) {
        const float* x_cur = (i == 0) ? x_in : out;
        const float* lw  = ln_w  + (size_t)i * DMODEL;
        const float* lb  = ln_b  + (size_t)i * DMODEL;
        const float* iw  = inw   + (size_t)i * 2 * DINNER * DMODEL;
        const float* cw  = convw + (size_t)i * DINNER * DCONV;
        const float* cb  = convb + (size_t)i * DINNER;
        const float* xw  = xpw   + (size_t)i * DBCW * DINNER;
        const float* dw  = dtw   + (size_t)i * DINNER * DTRANK;
        const float* db  = dtb   + (size_t)i * DINNER;
        const float* Al  = Alog  + (size_t)i * DINNER * DSTATE;
        const float* Dpp = Dp    + (size_t)i * DINNER;
        const float* ow  = outw  + (size_t)i * DMODEL * DINNER;

        // 1. LayerNorm
        ln_kernel<<<ROWS, blk256, 0, stream>>>(x_cur, lw, lb, xn);
        // 2. in_proj: xz = xn @ iw^T   (M=16384, N=2048, K=512)
        gemm_tn<false><<<dim3(2 * DINNER / 64, ROWS / 64), blk256, 0, stream>>>(
            xn, iw, nullptr, xz, ROWS, 2 * DINNER, DMODEL);
        // 3. x_proj with fused conv+SiLU on A: dbc = conv_silu(xz) @ xw^T  (M=16384, N=64, K=1024)
        gemm_xproj<<<ROWS / 64, blk256, 0, stream>>>(xz, xw, cw, cb, dbc);
        // 4. fused scan (conv+SiLU recompute, dt_proj+softplus, scan, gate)
        scan_fused<<<(B_SZ * DINNER) / 16, blk256, 0, stream>>>(
            xz, dbc, cw, cb, dw, db, Al, Dpp, ybuf);
        // 5. out_proj + residual: out = x_cur + ybuf @ ow^T  (M=16384, N=512, K=1024)
        gemm_tn<true><<<dim3(DMODEL / 64, ROWS / 64), blk256, 0, stream>>>(
            ybuf, ow, x_cur, out, ROWS, DMODEL, DINNER);
    }
}

// Round 3
// 5687.086 us; speedup vs baseline: 1.2927x; 1.2927x over previous
//
#include <hip/hip_runtime.h>
#include <hip/hip_bf16.h>
#include <math.h>

// Problem constants
#define B_SZ   8
#define SEQ    2048
#define DMODEL 512
#define DEPTH  2
#define DSTATE 16
#define DCONV  4
#define DINNER 1024
#define DTRANK 32
#define ROWS   (B_SZ * SEQ)          // 16384
#define DBCW   (DTRANK + 2 * DSTATE) // 64

__device__ __forceinline__ float silu_f(float v) {
    return v / (1.f + expf(-v));
}

// ---------------------------------------------------------------- LayerNorm
__global__ __launch_bounds__(256) void ln_kernel(const float* __restrict__ x,
                                                 const float* __restrict__ w,
                                                 const float* __restrict__ b,
                                                 float* __restrict__ out) {
    int r = blockIdx.x;
    int tid = threadIdx.x;
    const float* xr = x + (size_t)r * DMODEL;
    float2 v = *(const float2*)(xr + tid * 2);
    float s = v.x + v.y;
    float s2 = v.x * v.x + v.y * v.y;
    #pragma unroll
    for (int off = 1; off < 64; off <<= 1) {
        s  += __shfl_xor(s, off);
        s2 += __shfl_xor(s2, off);
    }
    __shared__ float ws[4], ws2[4];
    int wid = tid >> 6, lane = tid & 63;
    if (lane == 0) { ws[wid] = s; ws2[wid] = s2; }
    __syncthreads();
    float ts = ws[0] + ws[1] + ws[2] + ws[3];
    float ts2 = ws2[0] + ws2[1] + ws2[2] + ws2[3];
    float mean = ts * (1.f / DMODEL);
    float var = ts2 * (1.f / DMODEL) - mean * mean;
    float inv = rsqrtf(var + 1e-5f);
    float2 o;
    o.x = (v.x - mean) * inv * w[tid * 2] + b[tid * 2];
    o.y = (v.y - mean) * inv * w[tid * 2 + 1] + b[tid * 2 + 1];
    *(float2*)(out + (size_t)r * DMODEL + tid * 2) = o;
}

// ---------------------------------------------------------------- GEMM  C = A(MxK) * W(NxK)^T  (+ res)
// BM=BN=64, BK=16, 256 threads, 4x4 microtile per thread.
template <bool RES>
__global__ __launch_bounds__(256) void gemm_tn(const float* __restrict__ A,
                                               const float* __restrict__ W,
                                               const float* __restrict__ res,
                                               float* __restrict__ C,
                                               int M, int N, int K) {
    __shared__ float As[16][64];
    __shared__ float Bs[16][64];
    int tid = threadIdx.x;
    int n0 = blockIdx.x * 64;
    int m0 = blockIdx.y * 64;
    int tx = tid & 15, ty = tid >> 4;
    int lr = tid >> 2;          // 0..63 tile row
    int lk = (tid & 3) * 4;     // 0,4,8,12
    const float* Aptr = A + (size_t)(m0 + lr) * K + lk;
    const float* Wptr = W + (size_t)(n0 + lr) * K + lk;
    float acc[4][4] = {};
    for (int k0 = 0; k0 < K; k0 += 16) {
        float4 av = *(const float4*)(Aptr + k0);
        float4 bv = *(const float4*)(Wptr + k0);
        __syncthreads();
        As[lk + 0][lr] = av.x; As[lk + 1][lr] = av.y;
        As[lk + 2][lr] = av.z; As[lk + 3][lr] = av.w;
        Bs[lk + 0][lr] = bv.x; Bs[lk + 1][lr] = bv.y;
        Bs[lk + 2][lr] = bv.z; Bs[lk + 3][lr] = bv.w;
        __syncthreads();
        #pragma unroll
        for (int kk = 0; kk < 16; ++kk) {
            float4 a = *(const float4*)&As[kk][ty * 4];
            float4 b = *(const float4*)&Bs[kk][tx * 4];
            float ar[4] = {a.x, a.y, a.z, a.w};
            float br[4] = {b.x, b.y, b.z, b.w};
            #pragma unroll
            for (int i = 0; i < 4; ++i)
                #pragma unroll
                for (int j = 0; j < 4; ++j)
                    acc[i][j] += ar[i] * br[j];
        }
    }
    #pragma unroll
    for (int i = 0; i < 4; ++i) {
        int m = m0 + ty * 4 + i;
        size_t off = (size_t)m * N + n0 + tx * 4;
        float4 v = {acc[i][0], acc[i][1], acc[i][2], acc[i][3]};
        if (RES) {
            float4 r4 = *(const float4*)(res + off);
            v.x += r4.x; v.y += r4.y; v.z += r4.z; v.w += r4.w;
        }
        *(float4*)(C + off) = v;
    }
}

// ---------------------------------------------------------------- x_proj GEMM with fused depthwise conv + SiLU on A
__global__ __launch_bounds__(256) void gemm_xproj(const float* __restrict__ xz,
                                                  const float* __restrict__ xpw,
                                                  const float* __restrict__ cw,
                                                  const float* __restrict__ cb,
                                                  float* __restrict__ dbc) {
    __shared__ float As[16][64];
    __shared__ float Bs[16][64];
    int tid = threadIdx.x;
    int m0 = blockIdx.x * 64;
    int tx = tid & 15, ty = tid >> 4;
    int lr = tid >> 2;          // 0..63
    int lk = (tid & 3) * 4;     // 0,4,8,12
    int r = m0 + lr;
    int l = r & (SEQ - 1);
    const float* xp = xz + (size_t)r * (2 * DINNER) + lk;
    const float* wp = xpw + (size_t)lr * DINNER + lk;   // lr = f row (N=64)
    float acc[4][4] = {};
    const float4 zero4 = {0.f, 0.f, 0.f, 0.f};
    for (int e0 = 0; e0 < DINNER; e0 += 16) {
        float4 x0  = *(const float4*)(xp + e0);
        float4 xm1 = (l >= 1) ? *(const float4*)(xp + e0 - 1 * 2 * DINNER) : zero4;
        float4 xm2 = (l >= 2) ? *(const float4*)(xp + e0 - 2 * 2 * DINNER) : zero4;
        float4 xm3 = (l >= 3) ? *(const float4*)(xp + e0 - 3 * 2 * DINNER) : zero4;
        float4 cb4 = *(const float4*)(cb + e0 + lk);
        float4 cwa = *(const float4*)(cw + (e0 + lk + 0) * 4);
        float4 cwb = *(const float4*)(cw + (e0 + lk + 1) * 4);
        float4 cwc = *(const float4*)(cw + (e0 + lk + 2) * 4);
        float4 cwd = *(const float4*)(cw + (e0 + lk + 3) * 4);
        float u0 = silu_f(cb4.x + cwa.x * xm3.x + cwa.y * xm2.x + cwa.z * xm1.x + cwa.w * x0.x);
        float u1 = silu_f(cb4.y + cwb.x * xm3.y + cwb.y * xm2.y + cwb.z * xm1.y + cwb.w * x0.y);
        float u2 = silu_f(cb4.z + cwc.x * xm3.z + cwc.y * xm2.z + cwc.z * xm1.z + cwc.w * x0.z);
        float u3 = silu_f(cb4.w + cwd.x * xm3.w + cwd.y * xm2.w + cwd.z * xm1.w + cwd.w * x0.w);
        float4 bv = *(const float4*)(wp + e0);
        __syncthreads();
        As[lk + 0][lr] = u0; As[lk + 1][lr] = u1;
        As[lk + 2][lr] = u2; As[lk + 3][lr] = u3;
        Bs[lk + 0][lr] = bv.x; Bs[lk + 1][lr] = bv.y;
        Bs[lk + 2][lr] = bv.z; Bs[lk + 3][lr] = bv.w;
        __syncthreads();
        #pragma unroll
        for (int kk = 0; kk < 16; ++kk) {
            float4 a = *(const float4*)&As[kk][ty * 4];
            float4 b = *(const float4*)&Bs[kk][tx * 4];
            float ar[4] = {a.x, a.y, a.z, a.w};
            float br[4] = {b.x, b.y, b.z, b.w};
            #pragma unroll
            for (int i = 0; i < 4; ++i)
                #pragma unroll
                for (int j = 0; j < 4; ++j)
                    acc[i][j] += ar[i] * br[j];
        }
    }
    #pragma unroll
    for (int i = 0; i < 4; ++i) {
        int m = m0 + ty * 4 + i;
        size_t off = (size_t)m * DBCW + tx * 4;
        float4 v = {acc[i][0], acc[i][1], acc[i][2], acc[i][3]};
        *(float4*)(dbc + off) = v;
    }
}

// ---------------------------------------------------------------- fused selective scan
// conv+SiLU (rolling window) + dt_proj + softplus + scan + gate, all in one.
// block: 256 threads = 16 (b,e) pairs x 16 states. 512 blocks.
// Double-buffered register queues with COMPILE-TIME buffer selection
// (round-2 lesson: runtime buffer index -> scratch spill, 20x slowdown).
#define SCHUNK 8

__device__ __forceinline__ void scan_load(const float* __restrict__ xp,
                                          const float* __restrict__ dp,
                                          int n,
                                          float (&qx)[SCHUNK], float (&qz)[SCHUNK],
                                          float (&qd0)[SCHUNK], float (&qd1)[SCHUNK],
                                          float (&qB)[SCHUNK], float (&qC)[SCHUNK]) {
    #pragma unroll
    for (int j = 0; j < SCHUNK; ++j) {
        qx[j] = xp[(size_t)j * (2 * DINNER)];
        qz[j] = xp[(size_t)j * (2 * DINNER) + DINNER];
        float2 d01 = *(const float2*)(dp + j * DBCW + 2 * n);
        qd0[j] = d01.x; qd1[j] = d01.y;
        qB[j] = dp[j * DBCW + DTRANK + n];
        qC[j] = dp[j * DBCW + DTRANK + DSTATE + n];
    }
}

__device__ __forceinline__ void scan_process(float (&qx)[SCHUNK], float (&qz)[SCHUNK],
                                             float (&qd0)[SCHUNK], float (&qd1)[SCHUNK],
                                             float (&qB)[SCHUNK], float (&qC)[SCHUNK],
                                             float& h, float& x1, float& x2, float& x3,
                                             float a, float w0, float w1, float w2, float w3,
                                             float cbe, float dtbe, float dpe,
                                             float dw0, float dw1, int n,
                                             float* __restrict__ yp_out) {
    #pragma unroll
    for (int j = 0; j < SCHUNK; ++j) {
        float xi = qx[j];
        float u = cbe + w0 * x3 + w1 * x2 + w2 * x1 + w3 * xi;
        x3 = x2; x2 = x1; x1 = xi;
        u = silu_f(u);
        float p = qd0[j] * dw0 + qd1[j] * dw1;
        p += __shfl_xor(p, 1);
        p += __shfl_xor(p, 2);
        p += __shfl_xor(p, 4);
        p += __shfl_xor(p, 8);
        float s = p + dtbe;
        float delta = (s > 20.f) ? s : log1pf(expf(s));
        float dA = expf(delta * a);
        h = dA * h + (delta * u) * qB[j];
        float yp = h * qC[j];
        yp += __shfl_xor(yp, 1);
        yp += __shfl_xor(yp, 2);
        yp += __shfl_xor(yp, 4);
        yp += __shfl_xor(yp, 8);
        if (n == 0) {
            yp_out[(size_t)j * DINNER] = (yp + u * dpe) * silu_f(qz[j]);
        }
    }
}

__global__ __launch_bounds__(256) void scan_fused(const float* __restrict__ xz,
                                                  const float* __restrict__ dbc,
                                                  const float* __restrict__ cw,
                                                  const float* __restrict__ cb,
                                                  const float* __restrict__ dtw,
                                                  const float* __restrict__ dtb,
                                                  const float* __restrict__ Alog,
                                                  const float* __restrict__ Dp,
                                                  float* __restrict__ y) {
    int tid = threadIdx.x;
    int pair = tid >> 4, n = tid & 15;
    int blk = blockIdx.x;
    int b = blk >> 6;                        // 64 e-groups per batch
    int e = ((blk & 63) << 4) + pair;
    float a = -expf(Alog[e * DSTATE + n]);
    float w0 = cw[e * 4 + 0], w1 = cw[e * 4 + 1], w2 = cw[e * 4 + 2], w3 = cw[e * 4 + 3];
    float cbe = cb[e], dtbe = dtb[e], dpe = Dp[e];
    float dw0 = dtw[e * DTRANK + 2 * n], dw1 = dtw[e * DTRANK + 2 * n + 1];
    const float* xzrow = xz + (size_t)b * SEQ * (2 * DINNER) + e;
    const float* dbrow = dbc + (size_t)b * SEQ * DBCW;
    float* yrow = y + (size_t)b * SEQ * DINNER + e;

    float h = 0.f, x1 = 0.f, x2 = 0.f, x3 = 0.f;
    // two register queue sets, selected only by literal code paths
    float Aqx[SCHUNK], Aqz[SCHUNK], Aqd0[SCHUNK], Aqd1[SCHUNK], AqB[SCHUNK], AqC[SCHUNK];
    float Bqx[SCHUNK], Bqz[SCHUNK], Bqd0[SCHUNK], Bqd1[SCHUNK], BqB[SCHUNK], BqC[SCHUNK];

    const int nc = SEQ / SCHUNK;   // 256, even
    scan_load(xzrow, dbrow, n, Aqx, Aqz, Aqd0, Aqd1, AqB, AqC);
    for (int c = 0; c < nc; c += 2) {
        // prefetch chunk c+1 into B while processing A
        scan_load(xzrow + (size_t)(c + 1) * SCHUNK * (2 * DINNER),
                  dbrow + (size_t)(c + 1) * SCHUNK * DBCW, n,
                  Bqx, Bqz, Bqd0, Bqd1, BqB, BqC);
        scan_process(Aqx, Aqz, Aqd0, Aqd1, AqB, AqC, h, x1, x2, x3,
                     a, w0, w1, w2, w3, cbe, dtbe, dpe, dw0, dw1, n,
                     yrow + (size_t)c * SCHUNK * DINNER);
        // prefetch chunk c+2 into A while processing B
        if (c + 2 < nc)
            scan_load(xzrow + (size_t)(c + 2) * SCHUNK * (2 * DINNER),
                      dbrow + (size_t)(c + 2) * SCHUNK * DBCW, n,
                      Aqx, Aqz, Aqd0, Aqd1, AqB, AqC);
        scan_process(Bqx, Bqz, Bqd0, Bqd1, BqB, BqC, h, x1, x2, x3,
                     a, w0, w1, w2, w3, cbe, dtbe, dpe, dw0, dw1, n,
                     yrow + (size_t)(c + 1) * SCHUNK * DINNER);
    }
}

// ---------------------------------------------------------------- launch
extern "C" void kernel_launch(void* const* d_in, const int* in_sizes, int n_in,
                              void* d_out, int out_size, void* d_ws, size_t ws_size,
                              hipStream_t stream) {
    const float* x_in   = (const float*)d_in[0];
    const float* ln_w   = (const float*)d_in[1];
    const float* ln_b   = (const float*)d_in[2];
    const float* inw    = (const float*)d_in[3];
    const float* convw  = (const float*)d_in[4];
    const float* convb  = (const float*)d_in[5];
    const float* xpw    = (const float*)d_in[6];
    const float* dtw    = (const float*)d_in[7];
    const float* dtb    = (const float*)d_in[8];
    const float* Alog   = (const float*)d_in[9];
    const float* Dp     = (const float*)d_in[10];
    const float* outw   = (const float*)d_in[11];
    float* out = (float*)d_out;

    // workspace carve-up (floats) — total 51,380,224 floats = 205.5 MB
    float* ws   = (float*)d_ws;
    float* xz   = ws;                                    // ROWS*2*DINNER = 33,554,432
    float* ybuf = xz + (size_t)ROWS * 2 * DINNER;        // ROWS*DINNER   = 16,777,216
    float* xn   = ybuf;                                  // alias: xn dead before scan writes ybuf
    float* dbc  = ybuf + (size_t)ROWS * DINNER;          // ROWS*DBCW     =  1,048,576

    const dim3 blk256(256);

    for (int i = 0; i < DEPTH; ++i) {
        const float* x_cur = (i == 0) ? x_in : out;
        const float* lw  = ln_w  + (size_t)i * DMODEL;
        const float* lb  = ln_b  + (size_t)i * DMODEL;
        const float* iw  = inw   + (size_t)i * 2 * DINNER * DMODEL;
        const float* cw  = convw + (size_t)i * DINNER * DCONV;
        const float* cb  = convb + (size_t)i * DINNER;
        const float* xw  = xpw   + (size_t)i * DBCW * DINNER;
        const float* dw  = dtw   + (size_t)i * DINNER * DTRANK;
        const float* db  = dtb   + (size_t)i * DINNER;
        const float* Al  = Alog  + (size_t)i * DINNER * DSTATE;
        const float* Dpp = Dp    + (size_t)i * DINNER;
        const float* ow  = outw  + (size_t)i * DMODEL * DINNER;

        // 1. LayerNorm
        ln_kernel<<<ROWS, blk256, 0, stream>>>(x_cur, lw, lb, xn);
        // 2. in_proj: xz = xn @ iw^T   (M=16384, N=2048, K=512)
        gemm_tn<false><<<dim3(2 * DINNER / 64, ROWS / 64), blk256, 0, stream>>>(
            xn, iw, nullptr, xz, ROWS, 2 * DINNER, DMODEL);
        // 3. x_proj with fused conv+SiLU on A: dbc = conv_silu(xz) @ xw^T  (M=16384, N=64, K=1024)
        gemm_xproj<<<ROWS / 64, blk256, 0, stream>>>(xz, xw, cw, cb, dbc);
        // 4. fused scan (conv+SiLU recompute, dt_proj+softplus, scan, gate)
        scan_fused<<<(B_SZ * DINNER) / 16, blk256, 0, stream>>>(
            xz, dbc, cw, cb, dw, db, Al, Dpp, ybuf);
        // 5. out_proj + residual: out = x_cur + ybuf @ ow^T  (M=16384, N=512, K=1024)
        gemm_tn<true><<<dim3(DMODEL / 64, ROWS / 64), blk256, 0, stream>>>(
            ybuf, ow, x_cur, out, ROWS, DMODEL, DINNER);
    }
}

// Round 4
// 3051.338 us; speedup vs baseline: 2.4094x; 1.8638x over previous
//
#include <hip/hip_runtime.h>
#include <hip/hip_bf16.h>
#include <math.h>

// Problem constants
#define B_SZ   8
#define SEQ    2048
#define DMODEL 512
#define DEPTH  2
#define DSTATE 16
#define DCONV  4
#define DINNER 1024
#define DTRANK 32
#define ROWS   (B_SZ * SEQ)          // 16384
#define DBCW   (DTRANK + 2 * DSTATE) // 64

// Fast device math (tolerance is ~2e-3; native v_exp/v_log/v_rcp are ~1 ulp)
__device__ __forceinline__ float silu_f(float v) {
    return v * __builtin_amdgcn_rcpf(1.f + __expf(-v));
}
__device__ __forceinline__ float softplus_f(float s) {
    return (s > 20.f) ? s : __logf(1.f + __expf(s));
}
// sum across the 16-lane state group (DPP row rotate-reduce; groups are row-aligned)
__device__ __forceinline__ float sum16(float x) {
    x += __int_as_float(__builtin_amdgcn_update_dpp(0, __float_as_int(x), 0x121, 0xf, 0xf, true));
    x += __int_as_float(__builtin_amdgcn_update_dpp(0, __float_as_int(x), 0x122, 0xf, 0xf, true));
    x += __int_as_float(__builtin_amdgcn_update_dpp(0, __float_as_int(x), 0x124, 0xf, 0xf, true));
    x += __int_as_float(__builtin_amdgcn_update_dpp(0, __float_as_int(x), 0x128, 0xf, 0xf, true));
    return x;
}

// ---------------------------------------------------------------- LayerNorm
__global__ __launch_bounds__(256) void ln_kernel(const float* __restrict__ x,
                                                 const float* __restrict__ w,
                                                 const float* __restrict__ b,
                                                 float* __restrict__ out) {
    int r = blockIdx.x;
    int tid = threadIdx.x;
    const float* xr = x + (size_t)r * DMODEL;
    float2 v = *(const float2*)(xr + tid * 2);
    float s = v.x + v.y;
    float s2 = v.x * v.x + v.y * v.y;
    #pragma unroll
    for (int off = 1; off < 64; off <<= 1) {
        s  += __shfl_xor(s, off);
        s2 += __shfl_xor(s2, off);
    }
    __shared__ float ws[4], ws2[4];
    int wid = tid >> 6, lane = tid & 63;
    if (lane == 0) { ws[wid] = s; ws2[wid] = s2; }
    __syncthreads();
    float ts = ws[0] + ws[1] + ws[2] + ws[3];
    float ts2 = ws2[0] + ws2[1] + ws2[2] + ws2[3];
    float mean = ts * (1.f / DMODEL);
    float var = ts2 * (1.f / DMODEL) - mean * mean;
    float inv = rsqrtf(var + 1e-5f);
    float2 o;
    o.x = (v.x - mean) * inv * w[tid * 2] + b[tid * 2];
    o.y = (v.y - mean) * inv * w[tid * 2 + 1] + b[tid * 2 + 1];
    *(float2*)(out + (size_t)r * DMODEL + tid * 2) = o;
}

// ---------------------------------------------------------------- GEMM  C = A(MxK) * W(NxK)^T  (+ res)
// BM=BN=64, BK=16, 256 threads, 4x4 microtile per thread.
template <bool RES>
__global__ __launch_bounds__(256) void gemm_tn(const float* __restrict__ A,
                                               const float* __restrict__ W,
                                               const float* __restrict__ res,
                                               float* __restrict__ C,
                                               int M, int N, int K) {
    __shared__ float As[16][64];
    __shared__ float Bs[16][64];
    int tid = threadIdx.x;
    int n0 = blockIdx.x * 64;
    int m0 = blockIdx.y * 64;
    int tx = tid & 15, ty = tid >> 4;
    int lr = tid >> 2;          // 0..63 tile row
    int lk = (tid & 3) * 4;     // 0,4,8,12
    const float* Aptr = A + (size_t)(m0 + lr) * K + lk;
    const float* Wptr = W + (size_t)(n0 + lr) * K + lk;
    float acc[4][4] = {};
    for (int k0 = 0; k0 < K; k0 += 16) {
        float4 av = *(const float4*)(Aptr + k0);
        float4 bv = *(const float4*)(Wptr + k0);
        __syncthreads();
        As[lk + 0][lr] = av.x; As[lk + 1][lr] = av.y;
        As[lk + 2][lr] = av.z; As[lk + 3][lr] = av.w;
        Bs[lk + 0][lr] = bv.x; Bs[lk + 1][lr] = bv.y;
        Bs[lk + 2][lr] = bv.z; Bs[lk + 3][lr] = bv.w;
        __syncthreads();
        #pragma unroll
        for (int kk = 0; kk < 16; ++kk) {
            float4 a = *(const float4*)&As[kk][ty * 4];
            float4 b = *(const float4*)&Bs[kk][tx * 4];
            float ar[4] = {a.x, a.y, a.z, a.w};
            float br[4] = {b.x, b.y, b.z, b.w};
            #pragma unroll
            for (int i = 0; i < 4; ++i)
                #pragma unroll
                for (int j = 0; j < 4; ++j)
                    acc[i][j] += ar[i] * br[j];
        }
    }
    #pragma unroll
    for (int i = 0; i < 4; ++i) {
        int m = m0 + ty * 4 + i;
        size_t off = (size_t)m * N + n0 + tx * 4;
        float4 v = {acc[i][0], acc[i][1], acc[i][2], acc[i][3]};
        if (RES) {
            float4 r4 = *(const float4*)(res + off);
            v.x += r4.x; v.y += r4.y; v.z += r4.z; v.w += r4.w;
        }
        *(float4*)(C + off) = v;
    }
}

// ---------------------------------------------------------------- x_proj GEMM with fused depthwise conv + SiLU on A
__global__ __launch_bounds__(256) void gemm_xproj(const float* __restrict__ xz,
                                                  const float* __restrict__ xpw,
                                                  const float* __restrict__ cw,
                                                  const float* __restrict__ cb,
                                                  float* __restrict__ dbc) {
    __shared__ float As[16][64];
    __shared__ float Bs[16][64];
    int tid = threadIdx.x;
    int m0 = blockIdx.x * 64;
    int tx = tid & 15, ty = tid >> 4;
    int lr = tid >> 2;          // 0..63
    int lk = (tid & 3) * 4;     // 0,4,8,12
    int r = m0 + lr;
    int l = r & (SEQ - 1);
    const float* xp = xz + (size_t)r * (2 * DINNER) + lk;
    const float* wp = xpw + (size_t)lr * DINNER + lk;   // lr = f row (N=64)
    float acc[4][4] = {};
    const float4 zero4 = {0.f, 0.f, 0.f, 0.f};
    for (int e0 = 0; e0 < DINNER; e0 += 16) {
        float4 x0  = *(const float4*)(xp + e0);
        float4 xm1 = (l >= 1) ? *(const float4*)(xp + e0 - 1 * 2 * DINNER) : zero4;
        float4 xm2 = (l >= 2) ? *(const float4*)(xp + e0 - 2 * 2 * DINNER) : zero4;
        float4 xm3 = (l >= 3) ? *(const float4*)(xp + e0 - 3 * 2 * DINNER) : zero4;
        float4 cb4 = *(const float4*)(cb + e0 + lk);
        float4 cwa = *(const float4*)(cw + (e0 + lk + 0) * 4);
        float4 cwb = *(const float4*)(cw + (e0 + lk + 1) * 4);
        float4 cwc = *(const float4*)(cw + (e0 + lk + 2) * 4);
        float4 cwd = *(const float4*)(cw + (e0 + lk + 3) * 4);
        float u0 = silu_f(cb4.x + cwa.x * xm3.x + cwa.y * xm2.x + cwa.z * xm1.x + cwa.w * x0.x);
        float u1 = silu_f(cb4.y + cwb.x * xm3.y + cwb.y * xm2.y + cwb.z * xm1.y + cwb.w * x0.y);
        float u2 = silu_f(cb4.z + cwc.x * xm3.z + cwc.y * xm2.z + cwc.z * xm1.z + cwc.w * x0.z);
        float u3 = silu_f(cb4.w + cwd.x * xm3.w + cwd.y * xm2.w + cwd.z * xm1.w + cwd.w * x0.w);
        float4 bv = *(const float4*)(wp + e0);
        __syncthreads();
        As[lk + 0][lr] = u0; As[lk + 1][lr] = u1;
        As[lk + 2][lr] = u2; As[lk + 3][lr] = u3;
        Bs[lk + 0][lr] = bv.x; Bs[lk + 1][lr] = bv.y;
        Bs[lk + 2][lr] = bv.z; Bs[lk + 3][lr] = bv.w;
        __syncthreads();
        #pragma unroll
        for (int kk = 0; kk < 16; ++kk) {
            float4 a = *(const float4*)&As[kk][ty * 4];
            float4 b = *(const float4*)&Bs[kk][tx * 4];
            float ar[4] = {a.x, a.y, a.z, a.w};
            float br[4] = {b.x, b.y, b.z, b.w};
            #pragma unroll
            for (int i = 0; i < 4; ++i)
                #pragma unroll
                for (int j = 0; j < 4; ++j)
                    acc[i][j] += ar[i] * br[j];
        }
    }
    #pragma unroll
    for (int i = 0; i < 4; ++i) {
        int m = m0 + ty * 4 + i;
        size_t off = (size_t)m * DBCW + tx * 4;
        float4 v = {acc[i][0], acc[i][1], acc[i][2], acc[i][3]};
        *(float4*)(dbc + off) = v;
    }
}

// ---------------------------------------------------------------- fused selective scan
// conv+SiLU (rolling window) + dt_proj + softplus + scan + gate, all in one.
// block: 256 threads = 16 (b,e) pairs x 16 states. 512 blocks.
// SCHUNK=4 double-buffered register queues (2x6x4=48 floats) with
// compile-time buffer selection; DPP rotate-reduce; native-instr math.
#define SCHUNK 4

__device__ __forceinline__ void scan_load(const float* __restrict__ xp,
                                          const float* __restrict__ dp,
                                          int n,
                                          float (&qx)[SCHUNK], float (&qz)[SCHUNK],
                                          float2 (&qd)[SCHUNK],
                                          float (&qB)[SCHUNK], float (&qC)[SCHUNK]) {
    #pragma unroll
    for (int j = 0; j < SCHUNK; ++j) {
        qx[j] = xp[(size_t)j * (2 * DINNER)];
        qz[j] = xp[(size_t)j * (2 * DINNER) + DINNER];
        qd[j] = *(const float2*)(dp + j * DBCW + 2 * n);
        qB[j] = dp[j * DBCW + DTRANK + n];
        qC[j] = dp[j * DBCW + DTRANK + DSTATE + n];
    }
}

__device__ __forceinline__ void scan_process(float (&qx)[SCHUNK], float (&qz)[SCHUNK],
                                             float2 (&qd)[SCHUNK],
                                             float (&qB)[SCHUNK], float (&qC)[SCHUNK],
                                             float& h, float& x1, float& x2, float& x3,
                                             float a, float w0, float w1, float w2, float w3,
                                             float cbe, float dtbe, float dpe,
                                             float dw0, float dw1, int n,
                                             float* __restrict__ yp_out) {
    #pragma unroll
    for (int j = 0; j < SCHUNK; ++j) {
        float xi = qx[j];
        float u = cbe + w0 * x3 + w1 * x2 + w2 * x1 + w3 * xi;
        x3 = x2; x2 = x1; x1 = xi;
        u = silu_f(u);
        float p = sum16(qd[j].x * dw0 + qd[j].y * dw1);
        float delta = softplus_f(p + dtbe);
        float dA = __expf(delta * a);
        h = dA * h + (delta * u) * qB[j];
        float yp = sum16(h * qC[j]);
        if (n == 0) {
            yp_out[(size_t)j * DINNER] = (yp + u * dpe) * silu_f(qz[j]);
        }
    }
}

__global__ __launch_bounds__(256, 2) void scan_fused(const float* __restrict__ xz,
                                                     const float* __restrict__ dbc,
                                                     const float* __restrict__ cw,
                                                     const float* __restrict__ cb,
                                                     const float* __restrict__ dtw,
                                                     const float* __restrict__ dtb,
                                                     const float* __restrict__ Alog,
                                                     const float* __restrict__ Dp,
                                                     float* __restrict__ y) {
    int tid = threadIdx.x;
    int pair = tid >> 4, n = tid & 15;
    int blk = blockIdx.x;
    int b = blk >> 6;                        // 64 e-groups per batch
    int e = ((blk & 63) << 4) + pair;
    float a = -__expf(Alog[e * DSTATE + n]);
    float w0 = cw[e * 4 + 0], w1 = cw[e * 4 + 1], w2 = cw[e * 4 + 2], w3 = cw[e * 4 + 3];
    float cbe = cb[e], dtbe = dtb[e], dpe = Dp[e];
    float dw0 = dtw[e * DTRANK + 2 * n], dw1 = dtw[e * DTRANK + 2 * n + 1];
    const float* xzrow = xz + (size_t)b * SEQ * (2 * DINNER) + e;
    const float* dbrow = dbc + (size_t)b * SEQ * DBCW;
    float* yrow = y + (size_t)b * SEQ * DINNER + e;

    float h = 0.f, x1 = 0.f, x2 = 0.f, x3 = 0.f;
    // two register queue sets, selected only by literal code paths
    float Aqx[SCHUNK], Aqz[SCHUNK], AqB[SCHUNK], AqC[SCHUNK];
    float Bqx[SCHUNK], Bqz[SCHUNK], BqB[SCHUNK], BqC[SCHUNK];
    float2 Aqd[SCHUNK], Bqd[SCHUNK];

    const int nc = SEQ / SCHUNK;   // 512, even
    scan_load(xzrow, dbrow, n, Aqx, Aqz, Aqd, AqB, AqC);
    for (int c = 0; c < nc; c += 2) {
        // prefetch chunk c+1 into B while processing A
        scan_load(xzrow + (size_t)(c + 1) * SCHUNK * (2 * DINNER),
                  dbrow + (size_t)(c + 1) * SCHUNK * DBCW, n,
                  Bqx, Bqz, Bqd, BqB, BqC);
        scan_process(Aqx, Aqz, Aqd, AqB, AqC, h, x1, x2, x3,
                     a, w0, w1, w2, w3, cbe, dtbe, dpe, dw0, dw1, n,
                     yrow + (size_t)c * SCHUNK * DINNER);
        // prefetch chunk c+2 into A while processing B
        if (c + 2 < nc)
            scan_load(xzrow + (size_t)(c + 2) * SCHUNK * (2 * DINNER),
                      dbrow + (size_t)(c + 2) * SCHUNK * DBCW, n,
                      Aqx, Aqz, Aqd, AqB, AqC);
        scan_process(Bqx, Bqz, Bqd, BqB, BqC, h, x1, x2, x3,
                     a, w0, w1, w2, w3, cbe, dtbe, dpe, dw0, dw1, n,
                     yrow + (size_t)(c + 1) * SCHUNK * DINNER);
    }
}

// ---------------------------------------------------------------- launch
extern "C" void kernel_launch(void* const* d_in, const int* in_sizes, int n_in,
                              void* d_out, int out_size, void* d_ws, size_t ws_size,
                              hipStream_t stream) {
    const float* x_in   = (const float*)d_in[0];
    const float* ln_w   = (const float*)d_in[1];
    const float* ln_b   = (const float*)d_in[2];
    const float* inw    = (const float*)d_in[3];
    const float* convw  = (const float*)d_in[4];
    const float* convb  = (const float*)d_in[5];
    const float* xpw    = (const float*)d_in[6];
    const float* dtw    = (const float*)d_in[7];
    const float* dtb    = (const float*)d_in[8];
    const float* Alog   = (const float*)d_in[9];
    const float* Dp     = (const float*)d_in[10];
    const float* outw   = (const float*)d_in[11];
    float* out = (float*)d_out;

    // workspace carve-up (floats) — total 51,380,224 floats = 205.5 MB
    float* ws   = (float*)d_ws;
    float* xz   = ws;                                    // ROWS*2*DINNER = 33,554,432
    float* ybuf = xz + (size_t)ROWS * 2 * DINNER;        // ROWS*DINNER   = 16,777,216
    float* xn   = ybuf;                                  // alias: xn dead before scan writes ybuf
    float* dbc  = ybuf + (size_t)ROWS * DINNER;          // ROWS*DBCW     =  1,048,576

    const dim3 blk256(256);

    for (int i = 0; i < DEPTH; ++i) {
        const float* x_cur = (i == 0) ? x_in : out;
        const float* lw  = ln_w  + (size_t)i * DMODEL;
        const float* lb  = ln_b  + (size_t)i * DMODEL;
        const float* iw  = inw   + (size_t)i * 2 * DINNER * DMODEL;
        const float* cw  = convw + (size_t)i * DINNER * DCONV;
        const float* cb  = convb + (size_t)i * DINNER;
        const float* xw  = xpw   + (size_t)i * DBCW * DINNER;
        const float* dw  = dtw   + (size_t)i * DINNER * DTRANK;
        const float* db  = dtb   + (size_t)i * DINNER;
        const float* Al  = Alog  + (size_t)i * DINNER * DSTATE;
        const float* Dpp = Dp    + (size_t)i * DINNER;
        const float* ow  = outw  + (size_t)i * DMODEL * DINNER;

        // 1. LayerNorm
        ln_kernel<<<ROWS, blk256, 0, stream>>>(x_cur, lw, lb, xn);
        // 2. in_proj: xz = xn @ iw^T   (M=16384, N=2048, K=512)
        gemm_tn<false><<<dim3(2 * DINNER / 64, ROWS / 64), blk256, 0, stream>>>(
            xn, iw, nullptr, xz, ROWS, 2 * DINNER, DMODEL);
        // 3. x_proj with fused conv+SiLU on A: dbc = conv_silu(xz) @ xw^T  (M=16384, N=64, K=1024)
        gemm_xproj<<<ROWS / 64, blk256, 0, stream>>>(xz, xw, cw, cb, dbc);
        // 4. fused scan (conv+SiLU recompute, dt_proj+softplus, scan, gate)
        scan_fused<<<(B_SZ * DINNER) / 16, blk256, 0, stream>>>(
            xz, dbc, cw, cb, dw, db, Al, Dpp, ybuf);
        // 5. out_proj + residual: out = x_cur + ybuf @ ow^T  (M=16384, N=512, K=1024)
        gemm_tn<true><<<dim3(DMODEL / 64, ROWS / 64), blk256, 0, stream>>>(
            ybuf, ow, x_cur, out, ROWS, DMODEL, DINNER);
    }
}

// Round 5
// 1796.327 us; speedup vs baseline: 4.0928x; 1.6987x over previous
//
#include <hip/hip_runtime.h>
#include <hip/hip_bf16.h>
#include <math.h>

// Problem constants
#define B_SZ   8
#define SEQ    2048
#define DMODEL 512
#define DEPTH  2
#define DSTATE 16
#define DCONV  4
#define DINNER 1024
#define DTRANK 32
#define ROWS   (B_SZ * SEQ)          // 16384
#define DBCW   (DTRANK + 2 * DSTATE) // 64

typedef unsigned short u16;
typedef float f32x4 __attribute__((ext_vector_type(4)));
typedef short bf16x8 __attribute__((ext_vector_type(8)));

// Fast device math (native v_exp/v_log/v_rcp)
__device__ __forceinline__ float silu_f(float v) {
    return v * __builtin_amdgcn_rcpf(1.f + __expf(-v));
}
__device__ __forceinline__ float softplus_f(float s) {
    return (s > 20.f) ? s : __logf(1.f + __expf(s));
}
// sum across the 16-lane state group (DPP row rotate-reduce)
__device__ __forceinline__ float sum16(float x) {
    x += __int_as_float(__builtin_amdgcn_update_dpp(0, __float_as_int(x), 0x121, 0xf, 0xf, true));
    x += __int_as_float(__builtin_amdgcn_update_dpp(0, __float_as_int(x), 0x122, 0xf, 0xf, true));
    x += __int_as_float(__builtin_amdgcn_update_dpp(0, __float_as_int(x), 0x124, 0xf, 0xf, true));
    x += __int_as_float(__builtin_amdgcn_update_dpp(0, __float_as_int(x), 0x128, 0xf, 0xf, true));
    return x;
}

__device__ __forceinline__ void load_lds16(const void* g, void* l) {
    __builtin_amdgcn_global_load_lds(
        (const __attribute__((address_space(1))) unsigned int*)g,
        (__attribute__((address_space(3))) unsigned int*)l, 16, 0, 0);
}

// ---------------------------------------------------------------- fp32 -> bf16 convert
__global__ __launch_bounds__(256) void f2bf(const float* __restrict__ in,
                                            __hip_bfloat16* __restrict__ out, int n) {
    int i = blockIdx.x * 256 + threadIdx.x;
    if (i < n) out[i] = __float2bfloat16(in[i]);
}

// ---------------------------------------------------------------- LayerNorm (bf16 out)
__global__ __launch_bounds__(256) void ln_kernel(const float* __restrict__ x,
                                                 const float* __restrict__ w,
                                                 const float* __restrict__ b,
                                                 __hip_bfloat16* __restrict__ out) {
    int r = blockIdx.x;
    int tid = threadIdx.x;
    const float* xr = x + (size_t)r * DMODEL;
    float2 v = *(const float2*)(xr + tid * 2);
    float s = v.x + v.y;
    float s2 = v.x * v.x + v.y * v.y;
    #pragma unroll
    for (int off = 1; off < 64; off <<= 1) {
        s  += __shfl_xor(s, off);
        s2 += __shfl_xor(s2, off);
    }
    __shared__ float ws[4], ws2[4];
    int wid = tid >> 6, lane = tid & 63;
    if (lane == 0) { ws[wid] = s; ws2[wid] = s2; }
    __syncthreads();
    float ts = ws[0] + ws[1] + ws[2] + ws[3];
    float ts2 = ws2[0] + ws2[1] + ws2[2] + ws2[3];
    float mean = ts * (1.f / DMODEL);
    float var = ts2 * (1.f / DMODEL) - mean * mean;
    float inv = rsqrtf(var + 1e-5f);
    out[(size_t)r * DMODEL + tid * 2]     = __float2bfloat16((v.x - mean) * inv * w[tid * 2] + b[tid * 2]);
    out[(size_t)r * DMODEL + tid * 2 + 1] = __float2bfloat16((v.y - mean) * inv * w[tid * 2 + 1] + b[tid * 2 + 1]);
}

// ---------------------------------------------------------------- bf16 MFMA GEMM
// C(MxN fp32) = A(MxK bf16) * W(NxK bf16)^T (+res fp32)
// 128x128 tile, BK=32, 256 threads = 4 waves (2x2 of 64x64).
// m97 structure: global_load_lds(16B) staging, 2-barrier K-loop,
// ds_read_b128 frags, 16x16x32 bf16 MFMA.
template <bool RES>
__global__ __launch_bounds__(256) void gemm_bf16(const u16* __restrict__ A,
                                                 const u16* __restrict__ W,
                                                 const float* __restrict__ res,
                                                 float* __restrict__ C,
                                                 int M, int N, int K) {
    __shared__ u16 As[128 * 32];
    __shared__ u16 Bs[128 * 32];
    int tid = threadIdx.x;
    int wave = tid >> 6, lane = tid & 63;
    int wm = (wave >> 1) * 64, wn = (wave & 1) * 64;
    int m0 = blockIdx.y * 128, n0 = blockIdx.x * 128;
    // staging: lane -> (row = lane/4, 16B segment = lane%4); 2 instrs cover 32 rows/wave
    int srow = lane >> 2, sseg = lane & 3;
    const u16* Ag = A + (size_t)(m0 + wave * 32 + srow) * K + sseg * 8;
    const u16* Wg = W + (size_t)(n0 + wave * 32 + srow) * K + sseg * 8;
    u16* Asw = As + wave * 32 * 32;   // wave-uniform LDS staging base
    u16* Bsw = Bs + wave * 32 * 32;

    f32x4 acc[4][4] = {};
    int col = lane & 15, quad = lane >> 4;

    for (int k0 = 0; k0 < K; k0 += 32) {
        __syncthreads();
        load_lds16(Ag + k0, Asw);
        load_lds16(Ag + k0 + (size_t)16 * K, Asw + 16 * 32);
        load_lds16(Wg + k0, Bsw);
        load_lds16(Wg + k0 + (size_t)16 * K, Bsw + 16 * 32);
        __syncthreads();
        bf16x8 af[4], bfr[4];
        #pragma unroll
        for (int i = 0; i < 4; ++i) {
            af[i]  = *(const bf16x8*)(As + (wm + i * 16 + col) * 32 + quad * 8);
            bfr[i] = *(const bf16x8*)(Bs + (wn + i * 16 + col) * 32 + quad * 8);
        }
        #pragma unroll
        for (int i = 0; i < 4; ++i)
            #pragma unroll
            for (int j = 0; j < 4; ++j)
                acc[i][j] = __builtin_amdgcn_mfma_f32_16x16x32_bf16(af[i], bfr[j], acc[i][j], 0, 0, 0);
    }
    // epilogue: C/D layout col=lane&15, row=quad*4+reg  [m89-verified]
    #pragma unroll
    for (int i = 0; i < 4; ++i) {
        int gm_base = m0 + wm + i * 16 + quad * 4;
        #pragma unroll
        for (int j = 0; j < 4; ++j) {
            int gn = n0 + wn + j * 16 + col;
            #pragma unroll
            for (int r = 0; r < 4; ++r) {
                size_t off = (size_t)(gm_base + r) * N + gn;
                float v = acc[i][j][r];
                if (RES) v += res[off];
                C[off] = v;
            }
        }
    }
}

// ---------------------------------------------------------------- x_proj GEMM with fused depthwise conv + SiLU on A (fp32)
__global__ __launch_bounds__(256) void gemm_xproj(const float* __restrict__ xz,
                                                  const float* __restrict__ xpw,
                                                  const float* __restrict__ cw,
                                                  const float* __restrict__ cb,
                                                  float* __restrict__ dbc) {
    __shared__ float Asl[16][64];
    __shared__ float Bsl[16][64];
    int tid = threadIdx.x;
    int m0 = blockIdx.x * 64;
    int tx = tid & 15, ty = tid >> 4;
    int lr = tid >> 2;          // 0..63
    int lk = (tid & 3) * 4;     // 0,4,8,12
    int r = m0 + lr;
    int l = r & (SEQ - 1);
    const float* xp = xz + (size_t)r * (2 * DINNER) + lk;
    const float* wp = xpw + (size_t)lr * DINNER + lk;   // lr = f row (N=64)
    float acc[4][4] = {};
    const float4 zero4 = {0.f, 0.f, 0.f, 0.f};
    for (int e0 = 0; e0 < DINNER; e0 += 16) {
        float4 x0  = *(const float4*)(xp + e0);
        float4 xm1 = (l >= 1) ? *(const float4*)(xp + e0 - 1 * 2 * DINNER) : zero4;
        float4 xm2 = (l >= 2) ? *(const float4*)(xp + e0 - 2 * 2 * DINNER) : zero4;
        float4 xm3 = (l >= 3) ? *(const float4*)(xp + e0 - 3 * 2 * DINNER) : zero4;
        float4 cb4 = *(const float4*)(cb + e0 + lk);
        float4 cwa = *(const float4*)(cw + (e0 + lk + 0) * 4);
        float4 cwb = *(const float4*)(cw + (e0 + lk + 1) * 4);
        float4 cwc = *(const float4*)(cw + (e0 + lk + 2) * 4);
        float4 cwd = *(const float4*)(cw + (e0 + lk + 3) * 4);
        float u0 = silu_f(cb4.x + cwa.x * xm3.x + cwa.y * xm2.x + cwa.z * xm1.x + cwa.w * x0.x);
        float u1 = silu_f(cb4.y + cwb.x * xm3.y + cwb.y * xm2.y + cwb.z * xm1.y + cwb.w * x0.y);
        float u2 = silu_f(cb4.z + cwc.x * xm3.z + cwc.y * xm2.z + cwc.z * xm1.z + cwc.w * x0.z);
        float u3 = silu_f(cb4.w + cwd.x * xm3.w + cwd.y * xm2.w + cwd.z * xm1.w + cwd.w * x0.w);
        float4 bv = *(const float4*)(wp + e0);
        __syncthreads();
        Asl[lk + 0][lr] = u0; Asl[lk + 1][lr] = u1;
        Asl[lk + 2][lr] = u2; Asl[lk + 3][lr] = u3;
        Bsl[lk + 0][lr] = bv.x; Bsl[lk + 1][lr] = bv.y;
        Bsl[lk + 2][lr] = bv.z; Bsl[lk + 3][lr] = bv.w;
        __syncthreads();
        #pragma unroll
        for (int kk = 0; kk < 16; ++kk) {
            float4 a = *(const float4*)&Asl[kk][ty * 4];
            float4 b = *(const float4*)&Bsl[kk][tx * 4];
            float ar[4] = {a.x, a.y, a.z, a.w};
            float br[4] = {b.x, b.y, b.z, b.w};
            #pragma unroll
            for (int i = 0; i < 4; ++i)
                #pragma unroll
                for (int j = 0; j < 4; ++j)
                    acc[i][j] += ar[i] * br[j];
        }
    }
    #pragma unroll
    for (int i = 0; i < 4; ++i) {
        int m = m0 + ty * 4 + i;
        size_t off = (size_t)m * DBCW + tx * 4;
        float4 v = {acc[i][0], acc[i][1], acc[i][2], acc[i][3]};
        *(float4*)(dbc + off) = v;
    }
}

// ---------------------------------------------------------------- fused selective scan
// block: 256 threads = 16 (b,e) pairs x 16 states. 512 blocks. Output bf16.
#define SCHUNK 4

__device__ __forceinline__ void scan_load(const float* __restrict__ xp,
                                          const float* __restrict__ dp,
                                          int n,
                                          float (&qx)[SCHUNK], float (&qz)[SCHUNK],
                                          float2 (&qd)[SCHUNK],
                                          float (&qB)[SCHUNK], float (&qC)[SCHUNK]) {
    #pragma unroll
    for (int j = 0; j < SCHUNK; ++j) {
        qx[j] = xp[(size_t)j * (2 * DINNER)];
        qz[j] = xp[(size_t)j * (2 * DINNER) + DINNER];
        qd[j] = *(const float2*)(dp + j * DBCW + 2 * n);
        qB[j] = dp[j * DBCW + DTRANK + n];
        qC[j] = dp[j * DBCW + DTRANK + DSTATE + n];
    }
}

__device__ __forceinline__ void scan_process(float (&qx)[SCHUNK], float (&qz)[SCHUNK],
                                             float2 (&qd)[SCHUNK],
                                             float (&qB)[SCHUNK], float (&qC)[SCHUNK],
                                             float& h, float& x1, float& x2, float& x3,
                                             float a, float w0, float w1, float w2, float w3,
                                             float cbe, float dtbe, float dpe,
                                             float dw0, float dw1, int n,
                                             __hip_bfloat16* __restrict__ yp_out) {
    #pragma unroll
    for (int j = 0; j < SCHUNK; ++j) {
        float xi = qx[j];
        float u = cbe + w0 * x3 + w1 * x2 + w2 * x1 + w3 * xi;
        x3 = x2; x2 = x1; x1 = xi;
        u = silu_f(u);
        float p = sum16(qd[j].x * dw0 + qd[j].y * dw1);
        float delta = softplus_f(p + dtbe);
        float dA = __expf(delta * a);
        h = dA * h + (delta * u) * qB[j];
        float yp = sum16(h * qC[j]);
        if (n == 0) {
            yp_out[(size_t)j * DINNER] = __float2bfloat16((yp + u * dpe) * silu_f(qz[j]));
        }
    }
}

__global__ __launch_bounds__(256, 2) void scan_fused(const float* __restrict__ xz,
                                                     const float* __restrict__ dbc,
                                                     const float* __restrict__ cw,
                                                     const float* __restrict__ cb,
                                                     const float* __restrict__ dtw,
                                                     const float* __restrict__ dtb,
                                                     const float* __restrict__ Alog,
                                                     const float* __restrict__ Dp,
                                                     __hip_bfloat16* __restrict__ y) {
    int tid = threadIdx.x;
    int pair = tid >> 4, n = tid & 15;
    int blk = blockIdx.x;
    int b = blk >> 6;                        // 64 e-groups per batch
    int e = ((blk & 63) << 4) + pair;
    float a = -__expf(Alog[e * DSTATE + n]);
    float w0 = cw[e * 4 + 0], w1 = cw[e * 4 + 1], w2 = cw[e * 4 + 2], w3 = cw[e * 4 + 3];
    float cbe = cb[e], dtbe = dtb[e], dpe = Dp[e];
    float dw0 = dtw[e * DTRANK + 2 * n], dw1 = dtw[e * DTRANK + 2 * n + 1];
    const float* xzrow = xz + (size_t)b * SEQ * (2 * DINNER) + e;
    const float* dbrow = dbc + (size_t)b * SEQ * DBCW;
    __hip_bfloat16* yrow = y + (size_t)b * SEQ * DINNER + e;

    float h = 0.f, x1 = 0.f, x2 = 0.f, x3 = 0.f;
    float Aqx[SCHUNK], Aqz[SCHUNK], AqB[SCHUNK], AqC[SCHUNK];
    float Bqx[SCHUNK], Bqz[SCHUNK], BqB[SCHUNK], BqC[SCHUNK];
    float2 Aqd[SCHUNK], Bqd[SCHUNK];

    const int nc = SEQ / SCHUNK;   // 512, even
    scan_load(xzrow, dbrow, n, Aqx, Aqz, Aqd, AqB, AqC);
    for (int c = 0; c < nc; c += 2) {
        scan_load(xzrow + (size_t)(c + 1) * SCHUNK * (2 * DINNER),
                  dbrow + (size_t)(c + 1) * SCHUNK * DBCW, n,
                  Bqx, Bqz, Bqd, BqB, BqC);
        scan_process(Aqx, Aqz, Aqd, AqB, AqC, h, x1, x2, x3,
                     a, w0, w1, w2, w3, cbe, dtbe, dpe, dw0, dw1, n,
                     yrow + (size_t)c * SCHUNK * DINNER);
        if (c + 2 < nc)
            scan_load(xzrow + (size_t)(c + 2) * SCHUNK * (2 * DINNER),
                      dbrow + (size_t)(c + 2) * SCHUNK * DBCW, n,
                      Aqx, Aqz, Aqd, AqB, AqC);
        scan_process(Bqx, Bqz, Bqd, BqB, BqC, h, x1, x2, x3,
                     a, w0, w1, w2, w3, cbe, dtbe, dpe, dw0, dw1, n,
                     yrow + (size_t)(c + 1) * SCHUNK * DINNER);
    }
}

// ---------------------------------------------------------------- launch
extern "C" void kernel_launch(void* const* d_in, const int* in_sizes, int n_in,
                              void* d_out, int out_size, void* d_ws, size_t ws_size,
                              hipStream_t stream) {
    const float* x_in   = (const float*)d_in[0];
    const float* ln_w   = (const float*)d_in[1];
    const float* ln_b   = (const float*)d_in[2];
    const float* inw    = (const float*)d_in[3];
    const float* convw  = (const float*)d_in[4];
    const float* convb  = (const float*)d_in[5];
    const float* xpw    = (const float*)d_in[6];
    const float* dtw    = (const float*)d_in[7];
    const float* dtb    = (const float*)d_in[8];
    const float* Alog   = (const float*)d_in[9];
    const float* Dp     = (const float*)d_in[10];
    const float* outw   = (const float*)d_in[11];
    float* out = (float*)d_out;

    // workspace carve-up — ~195 MB total
    float* xz  = (float*)d_ws;                               // 134,217,728 B
    float* dbc = xz + (size_t)ROWS * 2 * DINNER;             //   4,194,304 B
    __hip_bfloat16* xnbf   = (__hip_bfloat16*)(dbc + (size_t)ROWS * DBCW);   // 16.8 MB
    __hip_bfloat16* ybf    = xnbf + (size_t)ROWS * DMODEL;                   // 33.6 MB
    __hip_bfloat16* inwbf  = ybf + (size_t)ROWS * DINNER;                    //  4.2 MB
    __hip_bfloat16* outwbf = inwbf + (size_t)DEPTH * 2 * DINNER * DMODEL;    //  2.1 MB

    const dim3 blk256(256);
    const int n_inw  = DEPTH * 2 * DINNER * DMODEL;   // 2,097,152
    const int n_outw = DEPTH * DMODEL * DINNER;       // 1,048,576

    // convert weights to bf16 (both layers, once per call)
    f2bf<<<(n_inw + 255) / 256, blk256, 0, stream>>>(inw, inwbf, n_inw);
    f2bf<<<(n_outw + 255) / 256, blk256, 0, stream>>>(outw, outwbf, n_outw);

    for (int i = 0; i < DEPTH; ++i) {
        const float* x_cur = (i == 0) ? x_in : out;
        const float* lw  = ln_w  + (size_t)i * DMODEL;
        const float* lb  = ln_b  + (size_t)i * DMODEL;
        const float* cw  = convw + (size_t)i * DINNER * DCONV;
        const float* cb  = convb + (size_t)i * DINNER;
        const float* xw  = xpw   + (size_t)i * DBCW * DINNER;
        const float* dw  = dtw   + (size_t)i * DINNER * DTRANK;
        const float* db  = dtb   + (size_t)i * DINNER;
        const float* Al  = Alog  + (size_t)i * DINNER * DSTATE;
        const float* Dpp = Dp    + (size_t)i * DINNER;
        const u16* iwb = (const u16*)(inwbf  + (size_t)i * 2 * DINNER * DMODEL);
        const u16* owb = (const u16*)(outwbf + (size_t)i * DMODEL * DINNER);

        // 1. LayerNorm -> bf16
        ln_kernel<<<ROWS, blk256, 0, stream>>>(x_cur, lw, lb, xnbf);
        // 2. in_proj (bf16 MFMA): xz = xn @ iw^T   (M=16384, N=2048, K=512)
        gemm_bf16<false><<<dim3(2 * DINNER / 128, ROWS / 128), blk256, 0, stream>>>(
            (const u16*)xnbf, iwb, nullptr, xz, ROWS, 2 * DINNER, DMODEL);
        // 3. x_proj with fused conv+SiLU (fp32): dbc = conv_silu(xz) @ xw^T
        gemm_xproj<<<ROWS / 64, blk256, 0, stream>>>(xz, xw, cw, cb, dbc);
        // 4. fused scan -> bf16 ybuf
        scan_fused<<<(B_SZ * DINNER) / 16, blk256, 0, stream>>>(
            xz, dbc, cw, cb, dw, db, Al, Dpp, ybf);
        // 5. out_proj (bf16 MFMA) + residual: out = x_cur + ybuf @ ow^T  (N=512, K=1024)
        gemm_bf16<true><<<dim3(DMODEL / 128, ROWS / 128), blk256, 0, stream>>>(
            (const u16*)ybf, owb, x_cur, out, ROWS, DMODEL, DINNER);
    }
}

// Round 6
// 1551.735 us; speedup vs baseline: 4.7379x; 1.1576x over previous
//
#include <hip/hip_runtime.h>
#include <hip/hip_bf16.h>
#include <math.h>

// Problem constants
#define B_SZ   8
#define SEQ    2048
#define DMODEL 512
#define DEPTH  2
#define DSTATE 16
#define DCONV  4
#define DINNER 1024
#define DTRANK 32
#define ROWS   (B_SZ * SEQ)          // 16384
#define DBCW   (DTRANK + 2 * DSTATE) // 64

typedef unsigned short u16;
typedef float f32x4 __attribute__((ext_vector_type(4)));
typedef short bf16x8 __attribute__((ext_vector_type(8)));

// Fast device math (native v_exp/v_log/v_rcp)
__device__ __forceinline__ float silu_f(float v) {
    return v * __builtin_amdgcn_rcpf(1.f + __expf(-v));
}
__device__ __forceinline__ float softplus_f(float s) {
    return (s > 20.f) ? s : __logf(1.f + __expf(s));
}
__device__ __forceinline__ u16 f2b(float v) {
    __hip_bfloat16 h = __float2bfloat16(v);
    return *(u16*)&h;
}
__device__ __forceinline__ float b2f(u16 v) {
    __hip_bfloat16 h;
    *(u16*)&h = v;
    return __bfloat162float(h);
}
// sum across the 16-lane state group (DPP row rotate-reduce)
__device__ __forceinline__ float sum16(float x) {
    x += __int_as_float(__builtin_amdgcn_update_dpp(0, __float_as_int(x), 0x121, 0xf, 0xf, true));
    x += __int_as_float(__builtin_amdgcn_update_dpp(0, __float_as_int(x), 0x122, 0xf, 0xf, true));
    x += __int_as_float(__builtin_amdgcn_update_dpp(0, __float_as_int(x), 0x124, 0xf, 0xf, true));
    x += __int_as_float(__builtin_amdgcn_update_dpp(0, __float_as_int(x), 0x128, 0xf, 0xf, true));
    return x;
}

__device__ __forceinline__ void load_lds16(const void* g, void* l) {
    __builtin_amdgcn_global_load_lds(
        (const __attribute__((address_space(1))) unsigned int*)g,
        (__attribute__((address_space(3))) unsigned int*)l, 16, 0, 0);
}

// ---------------------------------------------------------------- fp32 -> bf16 convert
__global__ __launch_bounds__(256) void f2bf(const float* __restrict__ in,
                                            __hip_bfloat16* __restrict__ out, int n) {
    int i = blockIdx.x * 256 + threadIdx.x;
    if (i < n) out[i] = __float2bfloat16(in[i]);
}

// ---------------------------------------------------------------- LayerNorm (bf16 out)
__global__ __launch_bounds__(256) void ln_kernel(const float* __restrict__ x,
                                                 const float* __restrict__ w,
                                                 const float* __restrict__ b,
                                                 __hip_bfloat16* __restrict__ out) {
    int r = blockIdx.x;
    int tid = threadIdx.x;
    const float* xr = x + (size_t)r * DMODEL;
    float2 v = *(const float2*)(xr + tid * 2);
    float s = v.x + v.y;
    float s2 = v.x * v.x + v.y * v.y;
    #pragma unroll
    for (int off = 1; off < 64; off <<= 1) {
        s  += __shfl_xor(s, off);
        s2 += __shfl_xor(s2, off);
    }
    __shared__ float ws[4], ws2[4];
    int wid = tid >> 6, lane = tid & 63;
    if (lane == 0) { ws[wid] = s; ws2[wid] = s2; }
    __syncthreads();
    float ts = ws[0] + ws[1] + ws[2] + ws[3];
    float ts2 = ws2[0] + ws2[1] + ws2[2] + ws2[3];
    float mean = ts * (1.f / DMODEL);
    float var = ts2 * (1.f / DMODEL) - mean * mean;
    float inv = rsqrtf(var + 1e-5f);
    out[(size_t)r * DMODEL + tid * 2]     = __float2bfloat16((v.x - mean) * inv * w[tid * 2] + b[tid * 2]);
    out[(size_t)r * DMODEL + tid * 2 + 1] = __float2bfloat16((v.y - mean) * inv * w[tid * 2 + 1] + b[tid * 2 + 1]);
}

// ---------------------------------------------------------------- bf16 MFMA GEMM
// C(MxN fp32) = A(MxK bf16) * W(NxK bf16)^T (+res fp32)
// 128x128 tile, BK=32, 256 threads = 4 waves (2x2 of 64x64).
template <bool RES>
__global__ __launch_bounds__(256) void gemm_bf16(const u16* __restrict__ A,
                                                 const u16* __restrict__ W,
                                                 const float* __restrict__ res,
                                                 float* __restrict__ C,
                                                 int M, int N, int K) {
    __shared__ u16 As[128 * 32];
    __shared__ u16 Bs[128 * 32];
    int tid = threadIdx.x;
    int wave = tid >> 6, lane = tid & 63;
    int wm = (wave >> 1) * 64, wn = (wave & 1) * 64;
    int m0 = blockIdx.y * 128, n0 = blockIdx.x * 128;
    int srow = lane >> 2, sseg = lane & 3;
    const u16* Ag = A + (size_t)(m0 + wave * 32 + srow) * K + sseg * 8;
    const u16* Wg = W + (size_t)(n0 + wave * 32 + srow) * K + sseg * 8;
    u16* Asw = As + wave * 32 * 32;
    u16* Bsw = Bs + wave * 32 * 32;

    f32x4 acc[4][4] = {};
    int col = lane & 15, quad = lane >> 4;

    for (int k0 = 0; k0 < K; k0 += 32) {
        __syncthreads();
        load_lds16(Ag + k0, Asw);
        load_lds16(Ag + k0 + (size_t)16 * K, Asw + 16 * 32);
        load_lds16(Wg + k0, Bsw);
        load_lds16(Wg + k0 + (size_t)16 * K, Bsw + 16 * 32);
        __syncthreads();
        bf16x8 af[4], bfr[4];
        #pragma unroll
        for (int i = 0; i < 4; ++i) {
            af[i]  = *(const bf16x8*)(As + (wm + i * 16 + col) * 32 + quad * 8);
            bfr[i] = *(const bf16x8*)(Bs + (wn + i * 16 + col) * 32 + quad * 8);
        }
        #pragma unroll
        for (int i = 0; i < 4; ++i)
            #pragma unroll
            for (int j = 0; j < 4; ++j)
                acc[i][j] = __builtin_amdgcn_mfma_f32_16x16x32_bf16(af[i], bfr[j], acc[i][j], 0, 0, 0);
    }
    #pragma unroll
    for (int i = 0; i < 4; ++i) {
        int gm_base = m0 + wm + i * 16 + quad * 4;
        #pragma unroll
        for (int j = 0; j < 4; ++j) {
            int gn = n0 + wn + j * 16 + col;
            #pragma unroll
            for (int r = 0; r < 4; ++r) {
                size_t off = (size_t)(gm_base + r) * N + gn;
                float v = acc[i][j][r];
                if (RES) v += res[off];
                C[off] = v;
            }
        }
    }
}

// ---------------------------------------------------------------- x_proj GEMM with fused depthwise conv + SiLU on A (fp32)
__global__ __launch_bounds__(256) void gemm_xproj(const float* __restrict__ xz,
                                                  const float* __restrict__ xpw,
                                                  const float* __restrict__ cw,
                                                  const float* __restrict__ cb,
                                                  float* __restrict__ dbc) {
    __shared__ float Asl[16][64];
    __shared__ float Bsl[16][64];
    int tid = threadIdx.x;
    int m0 = blockIdx.x * 64;
    int tx = tid & 15, ty = tid >> 4;
    int lr = tid >> 2;
    int lk = (tid & 3) * 4;
    int r = m0 + lr;
    int l = r & (SEQ - 1);
    const float* xp = xz + (size_t)r * (2 * DINNER) + lk;
    const float* wp = xpw + (size_t)lr * DINNER + lk;
    float acc[4][4] = {};
    const float4 zero4 = {0.f, 0.f, 0.f, 0.f};
    for (int e0 = 0; e0 < DINNER; e0 += 16) {
        float4 x0  = *(const float4*)(xp + e0);
        float4 xm1 = (l >= 1) ? *(const float4*)(xp + e0 - 1 * 2 * DINNER) : zero4;
        float4 xm2 = (l >= 2) ? *(const float4*)(xp + e0 - 2 * 2 * DINNER) : zero4;
        float4 xm3 = (l >= 3) ? *(const float4*)(xp + e0 - 3 * 2 * DINNER) : zero4;
        float4 cb4 = *(const float4*)(cb + e0 + lk);
        float4 cwa = *(const float4*)(cw + (e0 + lk + 0) * 4);
        float4 cwb = *(const float4*)(cw + (e0 + lk + 1) * 4);
        float4 cwc = *(const float4*)(cw + (e0 + lk + 2) * 4);
        float4 cwd = *(const float4*)(cw + (e0 + lk + 3) * 4);
        float u0 = silu_f(cb4.x + cwa.x * xm3.x + cwa.y * xm2.x + cwa.z * xm1.x + cwa.w * x0.x);
        float u1 = silu_f(cb4.y + cwb.x * xm3.y + cwb.y * xm2.y + cwb.z * xm1.y + cwb.w * x0.y);
        float u2 = silu_f(cb4.z + cwc.x * xm3.z + cwc.y * xm2.z + cwc.z * xm1.z + cwc.w * x0.z);
        float u3 = silu_f(cb4.w + cwd.x * xm3.w + cwd.y * xm2.w + cwd.z * xm1.w + cwd.w * x0.w);
        float4 bv = *(const float4*)(wp + e0);
        __syncthreads();
        Asl[lk + 0][lr] = u0; Asl[lk + 1][lr] = u1;
        Asl[lk + 2][lr] = u2; Asl[lk + 3][lr] = u3;
        Bsl[lk + 0][lr] = bv.x; Bsl[lk + 1][lr] = bv.y;
        Bsl[lk + 2][lr] = bv.z; Bsl[lk + 3][lr] = bv.w;
        __syncthreads();
        #pragma unroll
        for (int kk = 0; kk < 16; ++kk) {
            float4 a = *(const float4*)&Asl[kk][ty * 4];
            float4 b = *(const float4*)&Bsl[kk][tx * 4];
            float ar[4] = {a.x, a.y, a.z, a.w};
            float br[4] = {b.x, b.y, b.z, b.w};
            #pragma unroll
            for (int i = 0; i < 4; ++i)
                #pragma unroll
                for (int j = 0; j < 4; ++j)
                    acc[i][j] += ar[i] * br[j];
        }
    }
    #pragma unroll
    for (int i = 0; i < 4; ++i) {
        int m = m0 + ty * 4 + i;
        size_t off = (size_t)m * DBCW + tx * 4;
        float4 v = {acc[i][0], acc[i][1], acc[i][2], acc[i][3]};
        *(float4*)(dbc + off) = v;
    }
}

// ---------------------------------------------------------------- delta precompute
// dlt[b,e,t] (bf16) = softplus(dot(dt[r,:32], dtw[e,:32]) + dtb[e]), r = b*SEQ+t
// grid: (DINNER/64, SEQ/256, B_SZ), block 256 (thread = t within chunk).
__global__ __launch_bounds__(256) void delta_t_kernel(const float* __restrict__ dbc,
                                                      const float* __restrict__ dtw,
                                                      const float* __restrict__ dtb,
                                                      u16* __restrict__ dlt) {
    __shared__ float wl[64 * 32];
    __shared__ float bl[64];
    int tid = threadIdx.x;
    int e0 = blockIdx.x * 64, t0 = blockIdx.y * 256, b = blockIdx.z;
    for (int i = tid; i < 64 * 32; i += 256) wl[i] = dtw[(size_t)e0 * DTRANK + i];
    if (tid < 64) bl[tid] = dtb[e0 + tid];
    float dreg[32];
    const float* dp = dbc + (size_t)(b * SEQ + t0 + tid) * DBCW;
    #pragma unroll
    for (int k = 0; k < 32; k += 4) {
        float4 v = *(const float4*)(dp + k);
        dreg[k] = v.x; dreg[k + 1] = v.y; dreg[k + 2] = v.z; dreg[k + 3] = v.w;
    }
    __syncthreads();
    for (int ep = 0; ep < 64; ++ep) {
        float s = bl[ep];
        #pragma unroll
        for (int k = 0; k < 32; ++k) s += dreg[k] * wl[ep * 32 + k];
        dlt[((size_t)b * DINNER + e0 + ep) * SEQ + t0 + tid] = f2b(softplus_f(s));
    }
}

// ---------------------------------------------------------------- B/C transpose to [b,n,t] bf16 (L2-resident, 512 KB each)
// grid: (SEQ/256, B_SZ), block 256.
__global__ __launch_bounds__(256) void bct_kernel(const float* __restrict__ dbc,
                                                  u16* __restrict__ Bt, u16* __restrict__ Ct) {
    int tid = threadIdx.x;
    int t = blockIdx.x * 256 + tid, b = blockIdx.y;
    const float* dp = dbc + (size_t)(b * SEQ + t) * DBCW + DTRANK;
    #pragma unroll
    for (int n = 0; n < DSTATE; ++n)
        Bt[((size_t)b * DSTATE + n) * SEQ + t] = f2b(dp[n]);
    #pragma unroll
    for (int n = 0; n < DSTATE; ++n)
        Ct[((size_t)b * DSTATE + n) * SEQ + t] = f2b(dp[DSTATE + n]);
}

// ---------------------------------------------------------------- slim selective scan
// conv+SiLU (rolling regs) + dA exp + h recurrence + sum16; writes RAW
// yp + u*D (fp32) in-place into the dead xi slots of xz (gate applied later).
// block: 256 threads = 16 (b,e) pairs x 16 states. 512 blocks.
#define SCHUNK 4

__device__ __forceinline__ void scan_load2(const float* xp, const u16* dlp,
                                           const u16* Bp, const u16* Cp,
                                           float (&qx)[SCHUNK], float (&qdl)[SCHUNK],
                                           float (&qB)[SCHUNK], float (&qC)[SCHUNK]) {
    #pragma unroll
    for (int j = 0; j < SCHUNK; ++j) qx[j] = xp[(size_t)j * (2 * DINNER)];
    ushort4 d4 = *(const ushort4*)dlp;
    ushort4 b4 = *(const ushort4*)Bp;
    ushort4 c4 = *(const ushort4*)Cp;
    qdl[0] = b2f(d4.x); qdl[1] = b2f(d4.y); qdl[2] = b2f(d4.z); qdl[3] = b2f(d4.w);
    qB[0]  = b2f(b4.x); qB[1]  = b2f(b4.y); qB[2]  = b2f(b4.z); qB[3]  = b2f(b4.w);
    qC[0]  = b2f(c4.x); qC[1]  = b2f(c4.y); qC[2]  = b2f(c4.z); qC[3]  = b2f(c4.w);
}

__device__ __forceinline__ void scan_proc2(float (&qx)[SCHUNK], float (&qdl)[SCHUNK],
                                           float (&qB)[SCHUNK], float (&qC)[SCHUNK],
                                           float& h, float& x1, float& x2, float& x3,
                                           float a, float w0, float w1, float w2, float w3,
                                           float cbe, float dpe, int n,
                                           float* ypout) {
    #pragma unroll
    for (int j = 0; j < SCHUNK; ++j) {
        float xi = qx[j];
        float u = cbe + w0 * x3 + w1 * x2 + w2 * x1 + w3 * xi;
        x3 = x2; x2 = x1; x1 = xi;
        u = silu_f(u);
        float dl = qdl[j];
        float dA = __expf(dl * a);
        h = dA * h + (dl * u) * qB[j];
        float yp = sum16(h * qC[j]);
        if (n == 0) ypout[(size_t)j * (2 * DINNER)] = yp + u * dpe;
    }
}

__global__ __launch_bounds__(256, 2) void scan_fused(float* xz,   // read xi / write yraw (aliased by design)
                                                     const u16* __restrict__ dlt,
                                                     const u16* __restrict__ Bt,
                                                     const u16* __restrict__ Ct,
                                                     const float* __restrict__ cw,
                                                     const float* __restrict__ cb,
                                                     const float* __restrict__ Alog,
                                                     const float* __restrict__ Dp) {
    int tid = threadIdx.x;
    int pair = tid >> 4, n = tid & 15;
    int blk = blockIdx.x;
    int b = blk >> 6;
    int e = ((blk & 63) << 4) + pair;
    float a = -__expf(Alog[e * DSTATE + n]);
    float w0 = cw[e * 4 + 0], w1 = cw[e * 4 + 1], w2 = cw[e * 4 + 2], w3 = cw[e * 4 + 3];
    float cbe = cb[e], dpe = Dp[e];
    float* xzrow = xz + (size_t)b * SEQ * (2 * DINNER) + e;   // xi read + yraw write
    const u16* dlrow = dlt + ((size_t)b * DINNER + e) * SEQ;
    const u16* Brow  = Bt + ((size_t)b * DSTATE + n) * SEQ;
    const u16* Crow  = Ct + ((size_t)b * DSTATE + n) * SEQ;

    float h = 0.f, x1 = 0.f, x2 = 0.f, x3 = 0.f;
    float Aqx[SCHUNK], Aqdl[SCHUNK], AqB[SCHUNK], AqC[SCHUNK];
    float Bqx[SCHUNK], Bqdl[SCHUNK], BqB[SCHUNK], BqC[SCHUNK];

    const int nc = SEQ / SCHUNK;   // 512, even
    scan_load2(xzrow, dlrow, Brow, Crow, Aqx, Aqdl, AqB, AqC);
    for (int c = 0; c < nc; c += 2) {
        scan_load2(xzrow + (size_t)(c + 1) * SCHUNK * (2 * DINNER),
                   dlrow + (c + 1) * SCHUNK, Brow + (c + 1) * SCHUNK, Crow + (c + 1) * SCHUNK,
                   Bqx, Bqdl, BqB, BqC);
        scan_proc2(Aqx, Aqdl, AqB, AqC, h, x1, x2, x3,
                   a, w0, w1, w2, w3, cbe, dpe, n,
                   xzrow + (size_t)c * SCHUNK * (2 * DINNER));
        if (c + 2 < nc)
            scan_load2(xzrow + (size_t)(c + 2) * SCHUNK * (2 * DINNER),
                       dlrow + (c + 2) * SCHUNK, Brow + (c + 2) * SCHUNK, Crow + (c + 2) * SCHUNK,
                       Aqx, Aqdl, AqB, AqC);
        scan_proc2(Bqx, Bqdl, BqB, BqC, h, x1, x2, x3,
                   a, w0, w1, w2, w3, cbe, dpe, n,
                   xzrow + (size_t)(c + 1) * SCHUNK * (2 * DINNER));
    }
}

// ---------------------------------------------------------------- gate: ybf = yraw * silu(z)  (bf16 out)
__global__ __launch_bounds__(256) void gate_kernel(const float* __restrict__ xz,
                                                   u16* __restrict__ ybf) {
    int idx = blockIdx.x * 256 + threadIdx.x;   // over ROWS*DINNER/4
    int r = idx >> 8;
    int e4 = (idx & 255) << 2;
    const float* row = xz + (size_t)r * (2 * DINNER);
    float4 yr = *(const float4*)(row + e4);
    float4 zz = *(const float4*)(row + DINNER + e4);
    ushort4 o;
    o.x = f2b(yr.x * silu_f(zz.x));
    o.y = f2b(yr.y * silu_f(zz.y));
    o.z = f2b(yr.z * silu_f(zz.z));
    o.w = f2b(yr.w * silu_f(zz.w));
    *(ushort4*)(ybf + (size_t)r * DINNER + e4) = o;
}

// ---------------------------------------------------------------- launch
extern "C" void kernel_launch(void* const* d_in, const int* in_sizes, int n_in,
                              void* d_out, int out_size, void* d_ws, size_t ws_size,
                              hipStream_t stream) {
    const float* x_in   = (const float*)d_in[0];
    const float* ln_w   = (const float*)d_in[1];
    const float* ln_b   = (const float*)d_in[2];
    const float* inw    = (const float*)d_in[3];
    const float* convw  = (const float*)d_in[4];
    const float* convb  = (const float*)d_in[5];
    const float* xpw    = (const float*)d_in[6];
    const float* dtw    = (const float*)d_in[7];
    const float* dtb    = (const float*)d_in[8];
    const float* Alog   = (const float*)d_in[9];
    const float* Dp     = (const float*)d_in[10];
    const float* outw   = (const float*)d_in[11];
    float* out = (float*)d_out;

    // workspace carve-up — 212,860,928 B = 203.0 MB (< known-good 205.5 MB)
    char* p = (char*)d_ws;
    float* xz  = (float*)p;                 p += (size_t)ROWS * 2 * DINNER * 4;   // 134,217,728
    float* dbc = (float*)p;                 p += (size_t)ROWS * DBCW * 4;         //   4,194,304
    u16*   dlt = (u16*)p;                   p += (size_t)B_SZ * DINNER * SEQ * 2; //  33,554,432
    u16*   Bt  = (u16*)p;                   p += (size_t)B_SZ * DSTATE * SEQ * 2; //     524,288
    u16*   Ct  = (u16*)p;                   p += (size_t)B_SZ * DSTATE * SEQ * 2; //     524,288
    u16*   ybf = (u16*)p;                   p += (size_t)ROWS * DINNER * 2;       //  33,554,432
    __hip_bfloat16* xnbf = (__hip_bfloat16*)ybf;  // alias: xn dead before scan/gate write ybf
    __hip_bfloat16* inwbf  = (__hip_bfloat16*)p;  p += (size_t)2 * DINNER * DMODEL * 2; // 4,194,304 (per-layer)
    __hip_bfloat16* outwbf = (__hip_bfloat16*)p;  p += (size_t)DMODEL * DINNER * 2;     // 2,097,152 (per-layer)

    const dim3 blk256(256);
    const int n_inw  = 2 * DINNER * DMODEL;   // per-layer 2,097,152
    const int n_outw = DMODEL * DINNER;       // per-layer 1,048,576

    for (int i = 0; i < DEPTH; ++i) {
        const float* x_cur = (i == 0) ? x_in : out;
        const float* lw  = ln_w  + (size_t)i * DMODEL;
        const float* lb  = ln_b  + (size_t)i * DMODEL;
        const float* iw  = inw   + (size_t)i * 2 * DINNER * DMODEL;
        const float* cw  = convw + (size_t)i * DINNER * DCONV;
        const float* cb  = convb + (size_t)i * DINNER;
        const float* xw  = xpw   + (size_t)i * DBCW * DINNER;
        const float* dw  = dtw   + (size_t)i * DINNER * DTRANK;
        const float* db  = dtb   + (size_t)i * DINNER;
        const float* Al  = Alog  + (size_t)i * DINNER * DSTATE;
        const float* Dpp = Dp    + (size_t)i * DINNER;
        const float* ow  = outw  + (size_t)i * DMODEL * DINNER;

        // 0. per-layer weight conversion to bf16
        f2bf<<<(n_inw + 255) / 256, blk256, 0, stream>>>(iw, inwbf, n_inw);
        f2bf<<<(n_outw + 255) / 256, blk256, 0, stream>>>(ow, outwbf, n_outw);
        // 1. LayerNorm -> bf16
        ln_kernel<<<ROWS, blk256, 0, stream>>>(x_cur, lw, lb, xnbf);
        // 2. in_proj (bf16 MFMA): xz = xn @ iw^T   (M=16384, N=2048, K=512)
        gemm_bf16<false><<<dim3(2 * DINNER / 128, ROWS / 128), blk256, 0, stream>>>(
            (const u16*)xnbf, (const u16*)inwbf, nullptr, xz, ROWS, 2 * DINNER, DMODEL);
        // 3. x_proj with fused conv+SiLU (fp32): dbc = conv_silu(xz) @ xw^T
        gemm_xproj<<<ROWS / 64, blk256, 0, stream>>>(xz, xw, cw, cb, dbc);
        // 4a. delta precompute (t-contiguous bf16)
        delta_t_kernel<<<dim3(DINNER / 64, SEQ / 256, B_SZ), blk256, 0, stream>>>(dbc, dw, db, dlt);
        // 4b. B/C transpose to [b,n,t] bf16
        bct_kernel<<<dim3(SEQ / 256, B_SZ), blk256, 0, stream>>>(dbc, Bt, Ct);
        // 5. slim scan: yraw (= yp + u*D) written in-place into xi slots of xz
        scan_fused<<<(B_SZ * DINNER) / 16, blk256, 0, stream>>>(
            xz, dlt, Bt, Ct, cw, cb, Al, Dpp);
        // 6. gate: ybf = yraw * silu(z)
        gate_kernel<<<(ROWS * DINNER / 4) / 256, blk256, 0, stream>>>(xz, ybf);
        // 7. out_proj (bf16 MFMA) + residual: out = x_cur + ybuf @ ow^T  (N=512, K=1024)
        gemm_bf16<true><<<dim3(DMODEL / 128, ROWS / 128), blk256, 0, stream>>>(
            ybf, (const u16*)outwbf, x_cur, out, ROWS, DMODEL, DINNER);
    }
}

// Round 7
// 1306.736 us; speedup vs baseline: 5.6262x; 1.1875x over previous
//
#include <hip/hip_runtime.h>
#include <hip/hip_bf16.h>
#include <math.h>

// Problem constants
#define B_SZ   8
#define SEQ    2048
#define DMODEL 512
#define DEPTH  2
#define DSTATE 16
#define DCONV  4
#define DINNER 1024
#define DTRANK 32
#define ROWS   (B_SZ * SEQ)          // 16384
#define DBCW   (DTRANK + 2 * DSTATE) // 64

typedef unsigned short u16;
typedef float f32x4 __attribute__((ext_vector_type(4)));
typedef short bf16x8 __attribute__((ext_vector_type(8)));

// Fast device math (native v_exp/v_log/v_rcp)
__device__ __forceinline__ float silu_f(float v) {
    return v * __builtin_amdgcn_rcpf(1.f + __expf(-v));
}
__device__ __forceinline__ float softplus_f(float s) {
    return (s > 20.f) ? s : __logf(1.f + __expf(s));
}
__device__ __forceinline__ u16 f2b(float v) {
    __hip_bfloat16 h = __float2bfloat16(v);
    return *(u16*)&h;
}
__device__ __forceinline__ float b2f(u16 v) {
    __hip_bfloat16 h;
    *(u16*)&h = v;
    return __bfloat162float(h);
}
// sum across the 16-lane state group (DPP row rotate-reduce)
__device__ __forceinline__ float sum16(float x) {
    x += __int_as_float(__builtin_amdgcn_update_dpp(0, __float_as_int(x), 0x121, 0xf, 0xf, true));
    x += __int_as_float(__builtin_amdgcn_update_dpp(0, __float_as_int(x), 0x122, 0xf, 0xf, true));
    x += __int_as_float(__builtin_amdgcn_update_dpp(0, __float_as_int(x), 0x124, 0xf, 0xf, true));
    x += __int_as_float(__builtin_amdgcn_update_dpp(0, __float_as_int(x), 0x128, 0xf, 0xf, true));
    return x;
}

__device__ __forceinline__ void load_lds16(const void* g, void* l) {
    __builtin_amdgcn_global_load_lds(
        (const __attribute__((address_space(1))) unsigned int*)g,
        (__attribute__((address_space(3))) unsigned int*)l, 16, 0, 0);
}

// ---------------------------------------------------------------- fp32 -> bf16 convert
__global__ __launch_bounds__(256) void f2bf(const float* __restrict__ in,
                                            __hip_bfloat16* __restrict__ out, int n) {
    int i = blockIdx.x * 256 + threadIdx.x;
    if (i < n) out[i] = __float2bfloat16(in[i]);
}

// ---------------------------------------------------------------- LayerNorm (bf16 out)
__global__ __launch_bounds__(256) void ln_kernel(const float* __restrict__ x,
                                                 const float* __restrict__ w,
                                                 const float* __restrict__ b,
                                                 __hip_bfloat16* __restrict__ out) {
    int r = blockIdx.x;
    int tid = threadIdx.x;
    const float* xr = x + (size_t)r * DMODEL;
    float2 v = *(const float2*)(xr + tid * 2);
    float s = v.x + v.y;
    float s2 = v.x * v.x + v.y * v.y;
    #pragma unroll
    for (int off = 1; off < 64; off <<= 1) {
        s  += __shfl_xor(s, off);
        s2 += __shfl_xor(s2, off);
    }
    __shared__ float ws[4], ws2[4];
    int wid = tid >> 6, lane = tid & 63;
    if (lane == 0) { ws[wid] = s; ws2[wid] = s2; }
    __syncthreads();
    float ts = ws[0] + ws[1] + ws[2] + ws[3];
    float ts2 = ws2[0] + ws2[1] + ws2[2] + ws2[3];
    float mean = ts * (1.f / DMODEL);
    float var = ts2 * (1.f / DMODEL) - mean * mean;
    float inv = rsqrtf(var + 1e-5f);
    out[(size_t)r * DMODEL + tid * 2]     = __float2bfloat16((v.x - mean) * inv * w[tid * 2] + b[tid * 2]);
    out[(size_t)r * DMODEL + tid * 2 + 1] = __float2bfloat16((v.y - mean) * inv * w[tid * 2 + 1] + b[tid * 2 + 1]);
}

// ---------------------------------------------------------------- bf16 MFMA GEMM
// C(MxN fp32) = A(MxK bf16, row pitch lda) * W(NxK bf16)^T (+res fp32)
// 128x128 tile, BK=32, 256 threads = 4 waves (2x2 of 64x64).
template <bool RES>
__global__ __launch_bounds__(256) void gemm_bf16(const u16* __restrict__ A, int lda,
                                                 const u16* __restrict__ W,
                                                 const float* __restrict__ res,
                                                 float* __restrict__ C,
                                                 int M, int N, int K) {
    __shared__ u16 As[128 * 32];
    __shared__ u16 Bs[128 * 32];
    int tid = threadIdx.x;
    int wave = tid >> 6, lane = tid & 63;
    int wm = (wave >> 1) * 64, wn = (wave & 1) * 64;
    int m0 = blockIdx.y * 128, n0 = blockIdx.x * 128;
    int srow = lane >> 2, sseg = lane & 3;
    const u16* Ag = A + (size_t)(m0 + wave * 32 + srow) * lda + sseg * 8;
    const u16* Wg = W + (size_t)(n0 + wave * 32 + srow) * K + sseg * 8;
    u16* Asw = As + wave * 32 * 32;
    u16* Bsw = Bs + wave * 32 * 32;

    f32x4 acc[4][4] = {};
    int col = lane & 15, quad = lane >> 4;

    for (int k0 = 0; k0 < K; k0 += 32) {
        __syncthreads();
        load_lds16(Ag + k0, Asw);
        load_lds16(Ag + k0 + (size_t)16 * lda, Asw + 16 * 32);
        load_lds16(Wg + k0, Bsw);
        load_lds16(Wg + k0 + (size_t)16 * K, Bsw + 16 * 32);
        __syncthreads();
        bf16x8 af[4], bfr[4];
        #pragma unroll
        for (int i = 0; i < 4; ++i) {
            af[i]  = *(const bf16x8*)(As + (wm + i * 16 + col) * 32 + quad * 8);
            bfr[i] = *(const bf16x8*)(Bs + (wn + i * 16 + col) * 32 + quad * 8);
        }
        #pragma unroll
        for (int i = 0; i < 4; ++i)
            #pragma unroll
            for (int j = 0; j < 4; ++j)
                acc[i][j] = __builtin_amdgcn_mfma_f32_16x16x32_bf16(af[i], bfr[j], acc[i][j], 0, 0, 0);
    }
    #pragma unroll
    for (int i = 0; i < 4; ++i) {
        int gm_base = m0 + wm + i * 16 + quad * 4;
        #pragma unroll
        for (int j = 0; j < 4; ++j) {
            int gn = n0 + wn + j * 16 + col;
            #pragma unroll
            for (int r = 0; r < 4; ++r) {
                size_t off = (size_t)(gm_base + r) * N + gn;
                float v = acc[i][j][r];
                if (RES) v += res[off];
                C[off] = v;
            }
        }
    }
}

// ---------------------------------------------------------------- x_proj GEMM with fused depthwise conv + SiLU on A (fp32)
__global__ __launch_bounds__(256) void gemm_xproj(const float* __restrict__ xz,
                                                  const float* __restrict__ xpw,
                                                  const float* __restrict__ cw,
                                                  const float* __restrict__ cb,
                                                  float* __restrict__ dbc) {
    __shared__ float Asl[16][64];
    __shared__ float Bsl[16][64];
    int tid = threadIdx.x;
    int m0 = blockIdx.x * 64;
    int tx = tid & 15, ty = tid >> 4;
    int lr = tid >> 2;
    int lk = (tid & 3) * 4;
    int r = m0 + lr;
    int l = r & (SEQ - 1);
    const float* xp = xz + (size_t)r * (2 * DINNER) + lk;
    const float* wp = xpw + (size_t)lr * DINNER + lk;
    float acc[4][4] = {};
    const float4 zero4 = {0.f, 0.f, 0.f, 0.f};
    for (int e0 = 0; e0 < DINNER; e0 += 16) {
        float4 x0  = *(const float4*)(xp + e0);
        float4 xm1 = (l >= 1) ? *(const float4*)(xp + e0 - 1 * 2 * DINNER) : zero4;
        float4 xm2 = (l >= 2) ? *(const float4*)(xp + e0 - 2 * 2 * DINNER) : zero4;
        float4 xm3 = (l >= 3) ? *(const float4*)(xp + e0 - 3 * 2 * DINNER) : zero4;
        float4 cb4 = *(const float4*)(cb + e0 + lk);
        float4 cwa = *(const float4*)(cw + (e0 + lk + 0) * 4);
        float4 cwb = *(const float4*)(cw + (e0 + lk + 1) * 4);
        float4 cwc = *(const float4*)(cw + (e0 + lk + 2) * 4);
        float4 cwd = *(const float4*)(cw + (e0 + lk + 3) * 4);
        float u0 = silu_f(cb4.x + cwa.x * xm3.x + cwa.y * xm2.x + cwa.z * xm1.x + cwa.w * x0.x);
        float u1 = silu_f(cb4.y + cwb.x * xm3.y + cwb.y * xm2.y + cwb.z * xm1.y + cwb.w * x0.y);
        float u2 = silu_f(cb4.z + cwc.x * xm3.z + cwc.y * xm2.z + cwc.z * xm1.z + cwc.w * x0.z);
        float u3 = silu_f(cb4.w + cwd.x * xm3.w + cwd.y * xm2.w + cwd.z * xm1.w + cwd.w * x0.w);
        float4 bv = *(const float4*)(wp + e0);
        __syncthreads();
        Asl[lk + 0][lr] = u0; Asl[lk + 1][lr] = u1;
        Asl[lk + 2][lr] = u2; Asl[lk + 3][lr] = u3;
        Bsl[lk + 0][lr] = bv.x; Bsl[lk + 1][lr] = bv.y;
        Bsl[lk + 2][lr] = bv.z; Bsl[lk + 3][lr] = bv.w;
        __syncthreads();
        #pragma unroll
        for (int kk = 0; kk < 16; ++kk) {
            float4 a = *(const float4*)&Asl[kk][ty * 4];
            float4 b = *(const float4*)&Bsl[kk][tx * 4];
            float ar[4] = {a.x, a.y, a.z, a.w};
            float br[4] = {b.x, b.y, b.z, b.w};
            #pragma unroll
            for (int i = 0; i < 4; ++i)
                #pragma unroll
                for (int j = 0; j < 4; ++j)
                    acc[i][j] += ar[i] * br[j];
        }
    }
    #pragma unroll
    for (int i = 0; i < 4; ++i) {
        int m = m0 + ty * 4 + i;
        size_t off = (size_t)m * DBCW + tx * 4;
        float4 v = {acc[i][0], acc[i][1], acc[i][2], acc[i][3]};
        *(float4*)(dbc + off) = v;
    }
}

// ---------------------------------------------------------------- u precompute: u[b,e,t] = silu(conv(xi)+cb), bf16 t-contiguous
// grid: (SEQ/64, DINNER/64, B_SZ), block 256. LDS tile + transpose.
__global__ __launch_bounds__(256) void u_t_kernel(const float* __restrict__ xz,
                                                  const float* __restrict__ cw,
                                                  const float* __restrict__ cb,
                                                  u16* __restrict__ ut) {
    __shared__ float xt[67][65];
    __shared__ u16 uo[64][70];
    int tid = threadIdx.x;
    int t0 = blockIdx.x * 64, e0 = blockIdx.y * 64, b = blockIdx.z;
    int er = tid & 63, rr = tid >> 6;
    for (int it = 0; it < 17; ++it) {
        int row = it * 4 + rr;
        if (row < 67) {
            int t = t0 + row - 3;
            xt[row][er] = (t >= 0) ? xz[((size_t)b * SEQ + t) * (2 * DINNER) + e0 + er] : 0.f;
        }
    }
    __syncthreads();
    {
        int e = tid & 63, tg = tid >> 6;
        float4 w4 = *(const float4*)(cw + (e0 + e) * 4);
        float cbe = cb[e0 + e];
        int tl0 = tg * 16;
        float x3 = xt[tl0][e], x2 = xt[tl0 + 1][e], x1 = xt[tl0 + 2][e];
        #pragma unroll
        for (int i = 0; i < 16; ++i) {
            float x0 = xt[tl0 + i + 3][e];
            float u = silu_f(cbe + w4.x * x3 + w4.y * x2 + w4.z * x1 + w4.w * x0);
            x3 = x2; x2 = x1; x1 = x0;
            uo[e][tl0 + i] = f2b(u);
        }
    }
    __syncthreads();
    {
        int tl = tid & 63, eg = tid >> 6;
        #pragma unroll
        for (int i = 0; i < 16; ++i) {
            int ee = eg * 16 + i;
            ut[((size_t)b * DINNER + e0 + ee) * SEQ + t0 + tl] = uo[ee][tl];
        }
    }
}

// ---------------------------------------------------------------- delta precompute
// dlt[b,e,t] (bf16) = softplus(dot(dt[r,:32], dtw[e,:32]) + dtb[e]), r = b*SEQ+t
__global__ __launch_bounds__(256) void delta_t_kernel(const float* __restrict__ dbc,
                                                      const float* __restrict__ dtw,
                                                      const float* __restrict__ dtb,
                                                      u16* __restrict__ dlt) {
    __shared__ float wl[64 * 32];
    __shared__ float bl[64];
    int tid = threadIdx.x;
    int e0 = blockIdx.x * 64, t0 = blockIdx.y * 256, b = blockIdx.z;
    for (int i = tid; i < 64 * 32; i += 256) wl[i] = dtw[(size_t)e0 * DTRANK + i];
    if (tid < 64) bl[tid] = dtb[e0 + tid];
    float dreg[32];
    const float* dp = dbc + (size_t)(b * SEQ + t0 + tid) * DBCW;
    #pragma unroll
    for (int k = 0; k < 32; k += 4) {
        float4 v = *(const float4*)(dp + k);
        dreg[k] = v.x; dreg[k + 1] = v.y; dreg[k + 2] = v.z; dreg[k + 3] = v.w;
    }
    __syncthreads();
    for (int ep = 0; ep < 64; ++ep) {
        float s = bl[ep];
        #pragma unroll
        for (int k = 0; k < 32; ++k) s += dreg[k] * wl[ep * 32 + k];
        dlt[((size_t)b * DINNER + e0 + ep) * SEQ + t0 + tid] = f2b(softplus_f(s));
    }
}

// ---------------------------------------------------------------- B/C transpose to [b,n,t] bf16
__global__ __launch_bounds__(256) void bct_kernel(const float* __restrict__ dbc,
                                                  u16* __restrict__ Bt, u16* __restrict__ Ct) {
    int tid = threadIdx.x;
    int t = blockIdx.x * 256 + tid, b = blockIdx.y;
    const float* dp = dbc + (size_t)(b * SEQ + t) * DBCW + DTRANK;
    #pragma unroll
    for (int n = 0; n < DSTATE; ++n)
        Bt[((size_t)b * DSTATE + n) * SEQ + t] = f2b(dp[n]);
    #pragma unroll
    for (int n = 0; n < DSTATE; ++n)
        Ct[((size_t)b * DSTATE + n) * SEQ + t] = f2b(dp[DSTATE + n]);
}

// ---------------------------------------------------------------- slim selective scan
// all inputs bf16 t-contiguous; per t: 1 exp + ~9 VALU + sum16.
// writes yraw = yp + u*D (fp32) into the dead xi slots of xz.
// block: 256 threads = 16 (b,e) pairs x 16 states. 512 blocks.
#define SCHUNK 8

__global__ __launch_bounds__(256, 2) void scan_fused(float* xz,
                                                     const u16* __restrict__ ut,
                                                     const u16* __restrict__ dlt,
                                                     const u16* __restrict__ Bt,
                                                     const u16* __restrict__ Ct,
                                                     const float* __restrict__ Alog,
                                                     const float* __restrict__ Dp) {
    int tid = threadIdx.x;
    int pair = tid >> 4, n = tid & 15;
    int blk = blockIdx.x;
    int b = blk >> 6;
    int e = ((blk & 63) << 4) + pair;
    float a = -__expf(Alog[e * DSTATE + n]);
    float dpe = Dp[e];
    const u16* urow  = ut  + ((size_t)b * DINNER + e) * SEQ;
    const u16* dlrow = dlt + ((size_t)b * DINNER + e) * SEQ;
    const u16* Brow  = Bt + ((size_t)b * DSTATE + n) * SEQ;
    const u16* Crow  = Ct + ((size_t)b * DSTATE + n) * SEQ;
    float* yrow = xz + (size_t)b * SEQ * (2 * DINNER) + e;

    float h = 0.f;
    bf16x8 Au, Adl, AB, AC, Bu, Bdl, BB, BC;

    auto load = [&](int c, bf16x8& u8, bf16x8& d8, bf16x8& b8, bf16x8& c8) {
        u8 = *(const bf16x8*)(urow + c * SCHUNK);
        d8 = *(const bf16x8*)(dlrow + c * SCHUNK);
        b8 = *(const bf16x8*)(Brow + c * SCHUNK);
        c8 = *(const bf16x8*)(Crow + c * SCHUNK);
    };
    auto proc = [&](int c, bf16x8 u8, bf16x8 d8, bf16x8 b8, bf16x8 c8) {
        float* yp_ = yrow + (size_t)c * SCHUNK * (2 * DINNER);
        #pragma unroll
        for (int j = 0; j < SCHUNK; ++j) {
            float uf = b2f((u16)u8[j]);
            float dl = b2f((u16)d8[j]);
            float dA = __expf(dl * a);
            h = dA * h + (dl * uf) * b2f((u16)b8[j]);
            float yp = sum16(h * b2f((u16)c8[j]));
            if (n == 0) yp_[(size_t)j * (2 * DINNER)] = yp + uf * dpe;
        }
    };

    const int nc = SEQ / SCHUNK;   // 256, even
    load(0, Au, Adl, AB, AC);
    for (int c = 0; c < nc; c += 2) {
        load(c + 1, Bu, Bdl, BB, BC);
        proc(c, Au, Adl, AB, AC);
        if (c + 2 < nc) load(c + 2, Au, Adl, AB, AC);
        proc(c + 1, Bu, Bdl, BB, BC);
    }
}

// ---------------------------------------------------------------- gate + in-place bf16 pack
// one block per row r: y_bf16[e] = yraw[e] * silu(z[e]) packed into row start.
__global__ __launch_bounds__(256) void gate_pack(float* xz) {
    int r = blockIdx.x, tid = threadIdx.x;
    float* row = xz + (size_t)r * (2 * DINNER);
    float4 yr = ((const float4*)row)[tid];
    float4 zz = ((const float4*)(row + DINNER))[tid];
    __syncthreads();   // all reads done before any packed write
    ushort4 o;
    o.x = f2b(yr.x * silu_f(zz.x));
    o.y = f2b(yr.y * silu_f(zz.y));
    o.z = f2b(yr.z * silu_f(zz.z));
    o.w = f2b(yr.w * silu_f(zz.w));
    ((ushort4*)row)[tid] = o;
}

// ---------------------------------------------------------------- launch
extern "C" void kernel_launch(void* const* d_in, const int* in_sizes, int n_in,
                              void* d_out, int out_size, void* d_ws, size_t ws_size,
                              hipStream_t stream) {
    const float* x_in   = (const float*)d_in[0];
    const float* ln_w   = (const float*)d_in[1];
    const float* ln_b   = (const float*)d_in[2];
    const float* inw    = (const float*)d_in[3];
    const float* convw  = (const float*)d_in[4];
    const float* convb  = (const float*)d_in[5];
    const float* xpw    = (const float*)d_in[6];
    const float* dtw    = (const float*)d_in[7];
    const float* dtb    = (const float*)d_in[8];
    const float* Alog   = (const float*)d_in[9];
    const float* Dp     = (const float*)d_in[10];
    const float* outw   = (const float*)d_in[11];
    float* out = (float*)d_out;

    // workspace carve-up — 212.9 MB total (same as round-6 proven size)
    char* p = (char*)d_ws;
    float* xz  = (float*)p;                 p += (size_t)ROWS * 2 * DINNER * 4;   // 134,217,728
    float* dbc = (float*)p;                 p += (size_t)ROWS * DBCW * 4;         //   4,194,304
    u16*   dlt = (u16*)p;                   p += (size_t)B_SZ * DINNER * SEQ * 2; //  33,554,432
    u16*   Bt  = (u16*)p;                   p += (size_t)B_SZ * DSTATE * SEQ * 2; //     524,288
    u16*   Ct  = (u16*)p;                   p += (size_t)B_SZ * DSTATE * SEQ * 2; //     524,288
    u16*   ut  = (u16*)p;                   p += (size_t)B_SZ * DINNER * SEQ * 2; //  33,554,432
    __hip_bfloat16* xnbf = (__hip_bfloat16*)ut;   // alias: xn dead before u_t writes ut
    __hip_bfloat16* inwbf  = (__hip_bfloat16*)p;  p += (size_t)2 * DINNER * DMODEL * 2; // 4,194,304
    __hip_bfloat16* outwbf = (__hip_bfloat16*)p;  p += (size_t)DMODEL * DINNER * 2;     // 2,097,152

    const dim3 blk256(256);
    const int n_inw  = 2 * DINNER * DMODEL;   // per-layer
    const int n_outw = DMODEL * DINNER;

    for (int i = 0; i < DEPTH; ++i) {
        const float* x_cur = (i == 0) ? x_in : out;
        const float* lw  = ln_w  + (size_t)i * DMODEL;
        const float* lb  = ln_b  + (size_t)i * DMODEL;
        const float* iw  = inw   + (size_t)i * 2 * DINNER * DMODEL;
        const float* cw  = convw + (size_t)i * DINNER * DCONV;
        const float* cb  = convb + (size_t)i * DINNER;
        const float* xw  = xpw   + (size_t)i * DBCW * DINNER;
        const float* dw  = dtw   + (size_t)i * DINNER * DTRANK;
        const float* db  = dtb   + (size_t)i * DINNER;
        const float* Al  = Alog  + (size_t)i * DINNER * DSTATE;
        const float* Dpp = Dp    + (size_t)i * DINNER;
        const float* ow  = outw  + (size_t)i * DMODEL * DINNER;

        // 0. per-layer weight conversion to bf16
        f2bf<<<(n_inw + 255) / 256, blk256, 0, stream>>>(iw, inwbf, n_inw);
        f2bf<<<(n_outw + 255) / 256, blk256, 0, stream>>>(ow, outwbf, n_outw);
        // 1. LayerNorm -> bf16 (into ut region; dead before u_t writes)
        ln_kernel<<<ROWS, blk256, 0, stream>>>(x_cur, lw, lb, xnbf);
        // 2. in_proj (bf16 MFMA): xz = xn @ iw^T   (M=16384, N=2048, K=512)
        gemm_bf16<false><<<dim3(2 * DINNER / 128, ROWS / 128), blk256, 0, stream>>>(
            (const u16*)xnbf, DMODEL, (const u16*)inwbf, nullptr, xz, ROWS, 2 * DINNER, DMODEL);
        // 3. x_proj with fused conv+SiLU (fp32): dbc = conv_silu(xz) @ xw^T
        gemm_xproj<<<ROWS / 64, blk256, 0, stream>>>(xz, xw, cw, cb, dbc);
        // 4a. u precompute (bf16 [b,e,t])
        u_t_kernel<<<dim3(SEQ / 64, DINNER / 64, B_SZ), blk256, 0, stream>>>(xz, cw, cb, ut);
        // 4b. delta precompute (bf16 [b,e,t])
        delta_t_kernel<<<dim3(DINNER / 64, SEQ / 256, B_SZ), blk256, 0, stream>>>(dbc, dw, db, dlt);
        // 4c. B/C transpose to [b,n,t] bf16
        bct_kernel<<<dim3(SEQ / 256, B_SZ), blk256, 0, stream>>>(dbc, Bt, Ct);
        // 5. slim scan: yraw = yp + u*D written into xi slots of xz
        scan_fused<<<(B_SZ * DINNER) / 16, blk256, 0, stream>>>(
            xz, ut, dlt, Bt, Ct, Al, Dpp);
        // 6. gate + pack bf16 y in-place into xz rows (pitch 4096 u16)
        gate_pack<<<ROWS, blk256, 0, stream>>>(xz);
        // 7. out_proj (bf16 MFMA, lda=4096) + residual
        gemm_bf16<true><<<dim3(DMODEL / 128, ROWS / 128), blk256, 0, stream>>>(
            (const u16*)xz, 2 * DINNER * 2, (const u16*)outwbf, x_cur, out, ROWS, DMODEL, DINNER);
    }
}

// Round 8
// 1054.805 us; speedup vs baseline: 6.9700x; 1.2388x over previous
//
#include <hip/hip_runtime.h>
#include <hip/hip_bf16.h>
#include <math.h>

// Problem constants
#define B_SZ   8
#define SEQ    2048
#define DMODEL 512
#define DEPTH  2
#define DSTATE 16
#define DCONV  4
#define DINNER 1024
#define DTRANK 32
#define ROWS   (B_SZ * SEQ)          // 16384
#define DBCW   (DTRANK + 2 * DSTATE) // 64

typedef unsigned short u16;
typedef float f32x4 __attribute__((ext_vector_type(4)));
typedef short bf16x8 __attribute__((ext_vector_type(8)));

// Fast device math (native v_exp/v_log/v_rcp)
__device__ __forceinline__ float silu_f(float v) {
    return v * __builtin_amdgcn_rcpf(1.f + __expf(-v));
}
__device__ __forceinline__ float softplus_f(float s) {
    return (s > 20.f) ? s : __logf(1.f + __expf(s));
}
__device__ __forceinline__ u16 f2b(float v) {
    __hip_bfloat16 h = __float2bfloat16(v);
    return *(u16*)&h;
}
__device__ __forceinline__ float b2f(u16 v) {
    __hip_bfloat16 h;
    *(u16*)&h = v;
    return __bfloat162float(h);
}
// sum across the 16-lane state group (DPP row rotate-reduce)
__device__ __forceinline__ float sum16(float x) {
    x += __int_as_float(__builtin_amdgcn_update_dpp(0, __float_as_int(x), 0x121, 0xf, 0xf, true));
    x += __int_as_float(__builtin_amdgcn_update_dpp(0, __float_as_int(x), 0x122, 0xf, 0xf, true));
    x += __int_as_float(__builtin_amdgcn_update_dpp(0, __float_as_int(x), 0x124, 0xf, 0xf, true));
    x += __int_as_float(__builtin_amdgcn_update_dpp(0, __float_as_int(x), 0x128, 0xf, 0xf, true));
    return x;
}

__device__ __forceinline__ void load_lds16(const void* g, void* l) {
    __builtin_amdgcn_global_load_lds(
        (const __attribute__((address_space(1))) unsigned int*)g,
        (__attribute__((address_space(3))) unsigned int*)l, 16, 0, 0);
}

// ---------------------------------------------------------------- fp32 -> bf16 convert
__global__ __launch_bounds__(256) void f2bf(const float* __restrict__ in,
                                            __hip_bfloat16* __restrict__ out, int n) {
    int i = blockIdx.x * 256 + threadIdx.x;
    if (i < n) out[i] = __float2bfloat16(in[i]);
}

// ---------------------------------------------------------------- LayerNorm (bf16 out)
__global__ __launch_bounds__(256) void ln_kernel(const float* __restrict__ x,
                                                 const float* __restrict__ w,
                                                 const float* __restrict__ b,
                                                 __hip_bfloat16* __restrict__ out) {
    int r = blockIdx.x;
    int tid = threadIdx.x;
    const float* xr = x + (size_t)r * DMODEL;
    float2 v = *(const float2*)(xr + tid * 2);
    float s = v.x + v.y;
    float s2 = v.x * v.x + v.y * v.y;
    #pragma unroll
    for (int off = 1; off < 64; off <<= 1) {
        s  += __shfl_xor(s, off);
        s2 += __shfl_xor(s2, off);
    }
    __shared__ float ws[4], ws2[4];
    int wid = tid >> 6, lane = tid & 63;
    if (lane == 0) { ws[wid] = s; ws2[wid] = s2; }
    __syncthreads();
    float ts = ws[0] + ws[1] + ws[2] + ws[3];
    float ts2 = ws2[0] + ws2[1] + ws2[2] + ws2[3];
    float mean = ts * (1.f / DMODEL);
    float var = ts2 * (1.f / DMODEL) - mean * mean;
    float inv = rsqrtf(var + 1e-5f);
    out[(size_t)r * DMODEL + tid * 2]     = __float2bfloat16((v.x - mean) * inv * w[tid * 2] + b[tid * 2]);
    out[(size_t)r * DMODEL + tid * 2 + 1] = __float2bfloat16((v.y - mean) * inv * w[tid * 2 + 1] + b[tid * 2 + 1]);
}

// ---------------------------------------------------------------- bf16 MFMA GEMM
// C(MxN fp32) = A(MxK bf16, row pitch lda) * W(NxK bf16)^T (+res fp32)
// 128x128 tile, BK=32, 256 threads = 4 waves (2x2 of 64x64).
template <bool RES>
__global__ __launch_bounds__(256) void gemm_bf16(const u16* __restrict__ A, int lda,
                                                 const u16* __restrict__ W,
                                                 const float* __restrict__ res,
                                                 float* __restrict__ C,
                                                 int M, int N, int K) {
    __shared__ u16 As[128 * 32];
    __shared__ u16 Bs[128 * 32];
    int tid = threadIdx.x;
    int wave = tid >> 6, lane = tid & 63;
    int wm = (wave >> 1) * 64, wn = (wave & 1) * 64;
    int m0 = blockIdx.y * 128, n0 = blockIdx.x * 128;
    int srow = lane >> 2, sseg = lane & 3;
    const u16* Ag = A + (size_t)(m0 + wave * 32 + srow) * lda + sseg * 8;
    const u16* Wg = W + (size_t)(n0 + wave * 32 + srow) * K + sseg * 8;
    u16* Asw = As + wave * 32 * 32;
    u16* Bsw = Bs + wave * 32 * 32;

    f32x4 acc[4][4] = {};
    int col = lane & 15, quad = lane >> 4;

    for (int k0 = 0; k0 < K; k0 += 32) {
        __syncthreads();
        load_lds16(Ag + k0, Asw);
        load_lds16(Ag + k0 + (size_t)16 * lda, Asw + 16 * 32);
        load_lds16(Wg + k0, Bsw);
        load_lds16(Wg + k0 + (size_t)16 * K, Bsw + 16 * 32);
        __syncthreads();
        bf16x8 af[4], bfr[4];
        #pragma unroll
        for (int i = 0; i < 4; ++i) {
            af[i]  = *(const bf16x8*)(As + (wm + i * 16 + col) * 32 + quad * 8);
            bfr[i] = *(const bf16x8*)(Bs + (wn + i * 16 + col) * 32 + quad * 8);
        }
        #pragma unroll
        for (int i = 0; i < 4; ++i)
            #pragma unroll
            for (int j = 0; j < 4; ++j)
                acc[i][j] = __builtin_amdgcn_mfma_f32_16x16x32_bf16(af[i], bfr[j], acc[i][j], 0, 0, 0);
    }
    #pragma unroll
    for (int i = 0; i < 4; ++i) {
        int gm_base = m0 + wm + i * 16 + quad * 4;
        #pragma unroll
        for (int j = 0; j < 4; ++j) {
            int gn = n0 + wn + j * 16 + col;
            #pragma unroll
            for (int r = 0; r < 4; ++r) {
                size_t off = (size_t)(gm_base + r) * N + gn;
                float v = acc[i][j][r];
                if (RES) v += res[off];
                C[off] = v;
            }
        }
    }
}

// ---------------------------------------------------------------- x_proj bf16 MFMA GEMM (N=64)
// dbc(ROWS x 64 fp32) = u_re(ROWS x 1024 bf16) * xpw(64 x 1024 bf16)^T
// BM=128, BN=64, BK=32, 256 threads = 4 waves stacked in M (each 32 rows x 64 cols).
__global__ __launch_bounds__(256) void gemm_xp_bf16(const u16* __restrict__ A,
                                                    const u16* __restrict__ W,
                                                    float* __restrict__ C) {
    __shared__ u16 As[128 * 32];
    __shared__ u16 Bs[64 * 32];
    int tid = threadIdx.x;
    int wave = tid >> 6, lane = tid & 63;
    int m0 = blockIdx.x * 128;
    int wm = wave * 32;
    int srow = lane >> 2, sseg = lane & 3;
    const u16* Ag = A + (size_t)(m0 + wm + srow) * DINNER + sseg * 8;
    const u16* Wg = W + (size_t)(wave * 16 + srow) * DINNER + sseg * 8;
    u16* Asw = As + wave * 32 * 32;
    u16* Bsw = Bs + wave * 16 * 32;

    f32x4 acc[2][4] = {};
    int col = lane & 15, quad = lane >> 4;

    for (int k0 = 0; k0 < DINNER; k0 += 32) {
        __syncthreads();
        load_lds16(Ag + k0, Asw);
        load_lds16(Ag + k0 + (size_t)16 * DINNER, Asw + 16 * 32);
        load_lds16(Wg + k0, Bsw);
        __syncthreads();
        bf16x8 af[2], bfr[4];
        #pragma unroll
        for (int i = 0; i < 2; ++i)
            af[i] = *(const bf16x8*)(As + (wm + i * 16 + col) * 32 + quad * 8);
        #pragma unroll
        for (int j = 0; j < 4; ++j)
            bfr[j] = *(const bf16x8*)(Bs + (j * 16 + col) * 32 + quad * 8);
        #pragma unroll
        for (int i = 0; i < 2; ++i)
            #pragma unroll
            for (int j = 0; j < 4; ++j)
                acc[i][j] = __builtin_amdgcn_mfma_f32_16x16x32_bf16(af[i], bfr[j], acc[i][j], 0, 0, 0);
    }
    #pragma unroll
    for (int i = 0; i < 2; ++i) {
        int gm_base = m0 + wm + i * 16 + quad * 4;
        #pragma unroll
        for (int j = 0; j < 4; ++j) {
            int gn = j * 16 + col;
            #pragma unroll
            for (int r = 0; r < 4; ++r)
                C[(size_t)(gm_base + r) * DBCW + gn] = acc[i][j][r];
        }
    }
}

// ---------------------------------------------------------------- u precompute
// u = silu(conv(xi)+cb): writes ut[b,e,t] (bf16, t-contig, for scan) AND
// u_re[r,e] (bf16 row-major, for x_proj MFMA GEMM).
// grid: (SEQ/64, DINNER/64, B_SZ), block 256. LDS tile + transpose.
__global__ __launch_bounds__(256) void u_t_kernel(const float* __restrict__ xz,
                                                  const float* __restrict__ cw,
                                                  const float* __restrict__ cb,
                                                  u16* __restrict__ ut,
                                                  u16* __restrict__ u_re) {
    __shared__ float xt[67][65];
    __shared__ u16 uo[64][70];
    int tid = threadIdx.x;
    int t0 = blockIdx.x * 64, e0 = blockIdx.y * 64, b = blockIdx.z;
    int er = tid & 63, rr = tid >> 6;
    for (int it = 0; it < 17; ++it) {
        int row = it * 4 + rr;
        if (row < 67) {
            int t = t0 + row - 3;
            xt[row][er] = (t >= 0) ? xz[((size_t)b * SEQ + t) * (2 * DINNER) + e0 + er] : 0.f;
        }
    }
    __syncthreads();
    {
        int e = tid & 63, tg = tid >> 6;
        float4 w4 = *(const float4*)(cw + (e0 + e) * 4);
        float cbe = cb[e0 + e];
        int tl0 = tg * 16;
        float x3 = xt[tl0][e], x2 = xt[tl0 + 1][e], x1 = xt[tl0 + 2][e];
        #pragma unroll
        for (int i = 0; i < 16; ++i) {
            float x0 = xt[tl0 + i + 3][e];
            float u = silu_f(cbe + w4.x * x3 + w4.y * x2 + w4.z * x1 + w4.w * x0);
            x3 = x2; x2 = x1; x1 = x0;
            u16 ub = f2b(u);
            uo[e][tl0 + i] = ub;
            // coalesced row-major write (consecutive lanes -> consecutive e)
            u_re[((size_t)b * SEQ + t0 + tl0 + i) * DINNER + e0 + e] = ub;
        }
    }
    __syncthreads();
    {
        int tl = tid & 63, eg = tid >> 6;
        #pragma unroll
        for (int i = 0; i < 16; ++i) {
            int ee = eg * 16 + i;
            ut[((size_t)b * DINNER + e0 + ee) * SEQ + t0 + tl] = uo[ee][tl];
        }
    }
}

// ---------------------------------------------------------------- delta precompute
// dlt[b,e,t] (bf16) = softplus(dot(dt[r,:32], dtw[e,:32]) + dtb[e]), r = b*SEQ+t
__global__ __launch_bounds__(256) void delta_t_kernel(const float* __restrict__ dbc,
                                                      const float* __restrict__ dtw,
                                                      const float* __restrict__ dtb,
                                                      u16* __restrict__ dlt) {
    __shared__ float wl[64 * 32];
    __shared__ float bl[64];
    int tid = threadIdx.x;
    int e0 = blockIdx.x * 64, t0 = blockIdx.y * 256, b = blockIdx.z;
    for (int i = tid; i < 64 * 32; i += 256) wl[i] = dtw[(size_t)e0 * DTRANK + i];
    if (tid < 64) bl[tid] = dtb[e0 + tid];
    float dreg[32];
    const float* dp = dbc + (size_t)(b * SEQ + t0 + tid) * DBCW;
    #pragma unroll
    for (int k = 0; k < 32; k += 4) {
        float4 v = *(const float4*)(dp + k);
        dreg[k] = v.x; dreg[k + 1] = v.y; dreg[k + 2] = v.z; dreg[k + 3] = v.w;
    }
    __syncthreads();
    for (int ep = 0; ep < 64; ++ep) {
        float s = bl[ep];
        #pragma unroll
        for (int k = 0; k < 32; ++k) s += dreg[k] * wl[ep * 32 + k];
        dlt[((size_t)b * DINNER + e0 + ep) * SEQ + t0 + tid] = f2b(softplus_f(s));
    }
}

// ---------------------------------------------------------------- B/C transpose to [b,n,t] bf16
__global__ __launch_bounds__(256) void bct_kernel(const float* __restrict__ dbc,
                                                  u16* __restrict__ Bt, u16* __restrict__ Ct) {
    int tid = threadIdx.x;
    int t = blockIdx.x * 256 + tid, b = blockIdx.y;
    const float* dp = dbc + (size_t)(b * SEQ + t) * DBCW + DTRANK;
    #pragma unroll
    for (int n = 0; n < DSTATE; ++n)
        Bt[((size_t)b * DSTATE + n) * SEQ + t] = f2b(dp[n]);
    #pragma unroll
    for (int n = 0; n < DSTATE; ++n)
        Ct[((size_t)b * DSTATE + n) * SEQ + t] = f2b(dp[DSTATE + n]);
}

// ---------------------------------------------------------------- slim selective scan
// bf16 t-contiguous inputs; 4 register buffer sets, prefetch distance 2 chunks.
// writes yraw = yp + u*D (fp32) into the dead xi slots of xz.
// block: 256 threads = 16 (b,e) pairs x 16 states. 512 blocks.
#define SCHUNK 8

__global__ __launch_bounds__(256, 2) void scan_fused(float* xz,
                                                     const u16* __restrict__ ut,
                                                     const u16* __restrict__ dlt,
                                                     const u16* __restrict__ Bt,
                                                     const u16* __restrict__ Ct,
                                                     const float* __restrict__ Alog,
                                                     const float* __restrict__ Dp) {
    int tid = threadIdx.x;
    int pair = tid >> 4, n = tid & 15;
    int blk = blockIdx.x;
    int b = blk >> 6;
    int e = ((blk & 63) << 4) + pair;
    float a = -__expf(Alog[e * DSTATE + n]);
    float dpe = Dp[e];
    const u16* urow  = ut  + ((size_t)b * DINNER + e) * SEQ;
    const u16* dlrow = dlt + ((size_t)b * DINNER + e) * SEQ;
    const u16* Brow  = Bt + ((size_t)b * DSTATE + n) * SEQ;
    const u16* Crow  = Ct + ((size_t)b * DSTATE + n) * SEQ;
    float* yrow = xz + (size_t)b * SEQ * (2 * DINNER) + e;

    float h = 0.f;
    bf16x8 Au, Adl, AB, AC, Bu, Bdl, BB, BC, Cu, Cdl, CB, CC, Du, Ddl, DB, DC;

    auto load = [&](int c, bf16x8& u8, bf16x8& d8, bf16x8& b8, bf16x8& c8) {
        u8 = *(const bf16x8*)(urow + c * SCHUNK);
        d8 = *(const bf16x8*)(dlrow + c * SCHUNK);
        b8 = *(const bf16x8*)(Brow + c * SCHUNK);
        c8 = *(const bf16x8*)(Crow + c * SCHUNK);
    };
    auto proc = [&](int c, bf16x8 u8, bf16x8 d8, bf16x8 b8, bf16x8 c8) {
        float* yp_ = yrow + (size_t)c * SCHUNK * (2 * DINNER);
        #pragma unroll
        for (int j = 0; j < SCHUNK; ++j) {
            float uf = b2f((u16)u8[j]);
            float dl = b2f((u16)d8[j]);
            float dA = __expf(dl * a);
            h = dA * h + (dl * uf) * b2f((u16)b8[j]);
            float yp = sum16(h * b2f((u16)c8[j]));
            if (n == 0) yp_[(size_t)j * (2 * DINNER)] = yp + uf * dpe;
        }
    };

    const int nc = SEQ / SCHUNK;   // 256, divisible by 4
    load(0, Au, Adl, AB, AC);
    load(1, Bu, Bdl, BB, BC);
    for (int c = 0; c < nc; c += 4) {
        if (c + 2 < nc) load(c + 2, Cu, Cdl, CB, CC);
        if (c + 3 < nc) load(c + 3, Du, Ddl, DB, DC);
        proc(c, Au, Adl, AB, AC);
        proc(c + 1, Bu, Bdl, BB, BC);
        if (c + 4 < nc) load(c + 4, Au, Adl, AB, AC);
        if (c + 5 < nc) load(c + 5, Bu, Bdl, BB, BC);
        proc(c + 2, Cu, Cdl, CB, CC);
        proc(c + 3, Du, Ddl, DB, DC);
    }
}

// ---------------------------------------------------------------- gate + in-place bf16 pack
__global__ __launch_bounds__(256) void gate_pack(float* xz) {
    int r = blockIdx.x, tid = threadIdx.x;
    float* row = xz + (size_t)r * (2 * DINNER);
    float4 yr = ((const float4*)row)[tid];
    float4 zz = ((const float4*)(row + DINNER))[tid];
    __syncthreads();   // all reads done before any packed write
    ushort4 o;
    o.x = f2b(yr.x * silu_f(zz.x));
    o.y = f2b(yr.y * silu_f(zz.y));
    o.z = f2b(yr.z * silu_f(zz.z));
    o.w = f2b(yr.w * silu_f(zz.w));
    ((ushort4*)row)[tid] = o;
}

// ---------------------------------------------------------------- launch
extern "C" void kernel_launch(void* const* d_in, const int* in_sizes, int n_in,
                              void* d_out, int out_size, void* d_ws, size_t ws_size,
                              hipStream_t stream) {
    const float* x_in   = (const float*)d_in[0];
    const float* ln_w   = (const float*)d_in[1];
    const float* ln_b   = (const float*)d_in[2];
    const float* inw    = (const float*)d_in[3];
    const float* convw  = (const float*)d_in[4];
    const float* convb  = (const float*)d_in[5];
    const float* xpw    = (const float*)d_in[6];
    const float* dtw    = (const float*)d_in[7];
    const float* dtb    = (const float*)d_in[8];
    const float* Alog   = (const float*)d_in[9];
    const float* Dp     = (const float*)d_in[10];
    const float* outw   = (const float*)d_in[11];
    float* out = (float*)d_out;

    // workspace carve-up — 212,860,928 B (round-6/7 proven footprint)
    char* p = (char*)d_ws;
    float* xz  = (float*)p;                 p += (size_t)ROWS * 2 * DINNER * 4;   // 134,217,728
    float* dbc = (float*)p;                 p += (size_t)ROWS * DBCW * 4;         //   4,194,304
    u16*   dlt = (u16*)p;                   p += (size_t)B_SZ * DINNER * SEQ * 2; //  33,554,432
    u16*   u_re = dlt;                      // alias: u_re consumed by x_proj before delta_t writes dlt
    u16*   Bt  = (u16*)p;                   p += (size_t)B_SZ * DSTATE * SEQ * 2; //     524,288
    u16*   Ct  = (u16*)p;                   p += (size_t)B_SZ * DSTATE * SEQ * 2; //     524,288
    u16*   ut  = (u16*)p;                   p += (size_t)B_SZ * DINNER * SEQ * 2; //  33,554,432
    __hip_bfloat16* xnbf = (__hip_bfloat16*)ut;   // alias: xn dead before u_t writes ut
    __hip_bfloat16* inwbf  = (__hip_bfloat16*)p;  p += (size_t)2 * DINNER * DMODEL * 2; // 4,194,304
    u16* xwbf = (u16*)inwbf;                // alias: xpw-bf16 written AFTER in_proj consumes inwbf
    __hip_bfloat16* outwbf = (__hip_bfloat16*)p;  p += (size_t)DMODEL * DINNER * 2;     // 2,097,152

    const dim3 blk256(256);
    const int n_inw  = 2 * DINNER * DMODEL;   // per-layer
    const int n_outw = DMODEL * DINNER;
    const int n_xw   = DBCW * DINNER;         // 65,536

    for (int i = 0; i < DEPTH; ++i) {
        const float* x_cur = (i == 0) ? x_in : out;
        const float* lw  = ln_w  + (size_t)i * DMODEL;
        const float* lb  = ln_b  + (size_t)i * DMODEL;
        const float* iw  = inw   + (size_t)i * 2 * DINNER * DMODEL;
        const float* cw  = convw + (size_t)i * DINNER * DCONV;
        const float* cb  = convb + (size_t)i * DINNER;
        const float* xw  = xpw   + (size_t)i * DBCW * DINNER;
        const float* dw  = dtw   + (size_t)i * DINNER * DTRANK;
        const float* db  = dtb   + (size_t)i * DINNER;
        const float* Al  = Alog  + (size_t)i * DINNER * DSTATE;
        const float* Dpp = Dp    + (size_t)i * DINNER;
        const float* ow  = outw  + (size_t)i * DMODEL * DINNER;

        // 0. weight conversion (in_proj / out_proj)
        f2bf<<<(n_inw + 255) / 256, blk256, 0, stream>>>(iw, inwbf, n_inw);
        f2bf<<<(n_outw + 255) / 256, blk256, 0, stream>>>(ow, outwbf, n_outw);
        // 1. LayerNorm -> bf16 (into ut region; dead before u_t writes)
        ln_kernel<<<ROWS, blk256, 0, stream>>>(x_cur, lw, lb, xnbf);
        // 2. in_proj (bf16 MFMA): xz = xn @ iw^T   (M=16384, N=2048, K=512)
        gemm_bf16<false><<<dim3(2 * DINNER / 128, ROWS / 128), blk256, 0, stream>>>(
            (const u16*)xnbf, DMODEL, (const u16*)inwbf, nullptr, xz, ROWS, 2 * DINNER, DMODEL);
        // 2b. x_proj weights -> bf16 (into inwbf region, now dead)
        f2bf<<<(n_xw + 255) / 256, blk256, 0, stream>>>(xw, (__hip_bfloat16*)xwbf, n_xw);
        // 3. u precompute: ut [b,e,t] + u_re [r,e] (u_re aliases dlt)
        u_t_kernel<<<dim3(SEQ / 64, DINNER / 64, B_SZ), blk256, 0, stream>>>(xz, cw, cb, ut, u_re);
        // 4. x_proj (bf16 MFMA, N=64): dbc = u_re @ xw^T
        gemm_xp_bf16<<<ROWS / 128, blk256, 0, stream>>>(u_re, xwbf, dbc);
        // 5a. delta precompute (bf16 [b,e,t]) — overwrites u_re region (now dead)
        delta_t_kernel<<<dim3(DINNER / 64, SEQ / 256, B_SZ), blk256, 0, stream>>>(dbc, dw, db, dlt);
        // 5b. B/C transpose to [b,n,t] bf16
        bct_kernel<<<dim3(SEQ / 256, B_SZ), blk256, 0, stream>>>(dbc, Bt, Ct);
        // 6. slim scan: yraw = yp + u*D written into xi slots of xz
        scan_fused<<<(B_SZ * DINNER) / 16, blk256, 0, stream>>>(
            xz, ut, dlt, Bt, Ct, Al, Dpp);
        // 7. gate + pack bf16 y in-place into xz rows (pitch 4096 u16)
        gate_pack<<<ROWS, blk256, 0, stream>>>(xz);
        // 8. out_proj (bf16 MFMA, lda=4096) + residual
        gemm_bf16<true><<<dim3(DMODEL / 128, ROWS / 128), blk256, 0, stream>>>(
            (const u16*)xz, 2 * DINNER * 2, (const u16*)outwbf, x_cur, out, ROWS, DMODEL, DINNER);
    }
}